// Round 11
// baseline (6461.391 us; speedup 1.0000x reference)
//
#include <hip/hip_runtime.h>
#include <hip/hip_bf16.h>

#define L_ITERS 15
#define DD 128
#define NNODES 50000
#define NEDGES 800000

typedef __attribute__((ext_vector_type(4))) float f32x4;
typedef __attribute__((ext_vector_type(8))) short bf16x8;

// Native bf16 converts: compiler emits HW cvt (and fuses v_cvt_pk_bf16_f32).
static __device__ __forceinline__ unsigned short f2bf(float f) {
  union { __bf16 b; unsigned short u; } c;
  c.b = (__bf16)f;
  return c.u;
}
static __device__ __forceinline__ float bf2f(unsigned short h) {
  union { unsigned short u; __bf16 b; } c;
  c.u = h;
  return (float)c.b;
}

// Pack f32 weight [L][K][128] into MFMA B-fragment order (bf16):
// lane l of k-step s, n-frag t holds B[s*32 + (l>>4)*8 + j][t*16 + (l&15)], j=0..7
__global__ void pack_w_kernel(const float* __restrict__ src,
                              unsigned short* __restrict__ dst, int K) {
  int total = L_ITERS * K * DD;
  for (int i = blockIdx.x * blockDim.x + threadIdx.x; i < total;
       i += gridDim.x * blockDim.x) {
    int layer = i / (K * DD);
    int rem = i - layer * K * DD;
    int k = rem / DD, n = rem - (rem / DD) * DD;
    int s = k >> 5, hi = (k >> 3) & 3, j = k & 7;
    int t = n >> 4, lane = hi * 16 + (n & 15);
    dst[layer * K * DD + ((s * 8 + t) * 64 + lane) * 8 + j] = f2bf(src[i]);
  }
}

// f32 [rows][128] -> bf16 rows with dst row stride (shorts)
__global__ void cvt_kernel(const float* __restrict__ src,
                           unsigned short* __restrict__ dst,
                           int nrows, int dstride) {
  int total = nrows * 16;
  for (int p = blockIdx.x * blockDim.x + threadIdx.x; p < total;
       p += gridDim.x * blockDim.x) {
    int r = p >> 4, w = p & 15;
    const float* s = src + (long long)r * DD + w * 8;
    f32x4 a = *(const f32x4*)s, b = *(const f32x4*)(s + 4);
    bf16x8 o;
    o[0] = (short)f2bf(a[0]); o[1] = (short)f2bf(a[1]);
    o[2] = (short)f2bf(a[2]); o[3] = (short)f2bf(a[3]);
    o[4] = (short)f2bf(b[0]); o[5] = (short)f2bf(b[1]);
    o[6] = (short)f2bf(b[2]); o[7] = (short)f2bf(b[3]);
    *(bf16x8*)(dst + (long long)r * dstride + w * 8) = o;
  }
}

// ---------- CSR preprocessing (once per call) ----------
__global__ void hist_kernel(const int* __restrict__ ei, int* __restrict__ cnt) {
  for (int e = blockIdx.x * blockDim.x + threadIdx.x; e < NEDGES;
       e += gridDim.x * blockDim.x)
    atomicAdd(&cnt[ei[NEDGES + e]], 1);
}

__global__ __launch_bounds__(1024) void scan_kernel(const int* __restrict__ cnt,
                                                    int* __restrict__ off,
                                                    int* __restrict__ cursor) {
  __shared__ int buf[1024];
  __shared__ int base;
  if (threadIdx.x == 0) { base = 0; off[0] = 0; }
  __syncthreads();
  for (int start = 0; start < NNODES; start += 1024) {
    int i = start + threadIdx.x;
    int v = (i < NNODES) ? cnt[i] : 0;
    buf[threadIdx.x] = v;
    __syncthreads();
    for (int d = 1; d < 1024; d <<= 1) {
      int t = (threadIdx.x >= d) ? buf[threadIdx.x - d] : 0;
      __syncthreads();
      buf[threadIdx.x] += t;
      __syncthreads();
    }
    if (i < NNODES) {
      int incl = base + buf[threadIdx.x];
      off[i + 1] = incl;
      cursor[i] = incl - v;   // exclusive start
    }
    __syncthreads();
    if (threadIdx.x == 0) base += buf[1023];
    __syncthreads();
  }
}

__global__ void scatter_kernel(const int* __restrict__ ei, int* __restrict__ cursor,
                               int* __restrict__ perm) {
  for (int e = blockIdx.x * blockDim.x + threadIdx.x; e < NEDGES;
       e += gridDim.x * blockDim.x) {
    int p = atomicAdd(&cursor[ei[NEDGES + e]], 1);
    perm[p] = e;
  }
}

// ---------- node-kernel GEMM pieces (plane-major [..][32][136]) ----------
template <int NS, int ROWS, int MI>
static __device__ __forceinline__ void gemm_step(
    const unsigned short* A, const unsigned short* __restrict__ pw,
    const float* __restrict__ bias, f32x4 (&acc)[MI][2],
    int lrow, int lhi, int lane, int wv, int wcol0) {
  float bv0 = bias[wcol0 + lrow];
  float bv1 = bias[wcol0 + 16 + lrow];
#pragma unroll
  for (int mi = 0; mi < MI; ++mi) {
    f32x4 z0, z1;
    z0[0] = bv0; z0[1] = bv0; z0[2] = bv0; z0[3] = bv0;
    z1[0] = bv1; z1[1] = bv1; z1[2] = bv1; z1[3] = bv1;
    acc[mi][0] = z0; acc[mi][1] = z1;
  }
  const unsigned short* bp = pw + (wv * 2 * 64 + lane) * 8;
#pragma unroll
  for (int s = 0; s < NS; ++s) {
    bf16x8 w0 = *(const bf16x8*)(bp + s * 4096);
    bf16x8 w1 = *(const bf16x8*)(bp + s * 4096 + 512);
    const unsigned short* ap = A + (s >> 2) * (ROWS * 136) + (s & 3) * 32 + lhi * 8;
#pragma unroll
    for (int mi = 0; mi < MI; ++mi) {
      bf16x8 a = *(const bf16x8*)(ap + (mi * 16 + lrow) * 136);
      acc[mi][0] = __builtin_amdgcn_mfma_f32_16x16x32_bf16(a, w0, acc[mi][0], 0, 0, 0);
      acc[mi][1] = __builtin_amdgcn_mfma_f32_16x16x32_bf16(a, w1, acc[mi][1], 0, 0, 0);
    }
  }
}

template <int MI>
static __device__ __forceinline__ void relu_store(const f32x4 (&acc)[MI][2],
                                                  unsigned short* H,
                                                  int lrow, int lhi, int wcol0) {
#pragma unroll
  for (int mi = 0; mi < MI; ++mi)
#pragma unroll
    for (int ni = 0; ni < 2; ++ni)
#pragma unroll
      for (int j = 0; j < 4; ++j)
        H[(mi * 16 + lhi * 4 + j) * 136 + wcol0 + ni * 16 + lrow] =
            f2bf(fmaxf(acc[mi][ni][j], 0.f));
}

// ---------- edge MLP: 64 edges/block, 8 waves x 16 cols, 3 LDS planes -------
// Identical memory shapes to the 4-wave version; each wave owns a 16-col
// slice (wcol0 = wv*16), doubling waves/SIMD for latency hiding.
template <bool LAST>
__global__ __launch_bounds__(512, 6) void edge_kernel(
    const unsigned short* __restrict__ xbf, unsigned short* easlot,
    const int* __restrict__ ei,
    const unsigned short* __restrict__ pw1,
    const unsigned short* __restrict__ pw2,
    const unsigned short* __restrict__ pw3,
    const float* __restrict__ b1, const float* __restrict__ b2,
    const float* __restrict__ b3, const float* __restrict__ gg,
    const float* __restrict__ bb) {
  __shared__ unsigned short sm[3 * 64 * 136];  // P0=x_src P1=x_dst P2=ea
  __shared__ float red[128];
  constexpr int PL = 64 * 136;
  const int tid = threadIdx.x, lane = tid & 63, wv = tid >> 6;  // wv 0..7
  const int lrow = lane & 15, lhi = lane >> 4, wcol0 = wv * 16;
  const int block0 = blockIdx.x * 64;   // NEDGES % 64 == 0

  if (tid < 128) red[tid] = 0.f;

  { // stage A: pure 16B bf16 copies; 8 threads/row, 6 pieces each
    int r = tid >> 3, q = tid & 7;
    long long e = block0 + r;
    const unsigned short* s0 = xbf + (long long)ei[e] * DD;
    const unsigned short* s1 = xbf + (long long)ei[NEDGES + e] * DD;
    const unsigned short* s2 = easlot + e * 256;
#pragma unroll
    for (int k = 0; k < 6; ++k) {
      int w = q + 8 * k;                  // 0..47
      int plane = w >> 4, off = (w & 15) * 8;
      const unsigned short* sp = (plane == 0) ? s0 : (plane == 1 ? s1 : s2);
      *(bf16x8*)(&sm[plane * PL + r * 136 + off]) = *(const bf16x8*)(sp + off);
    }
  }
  __syncthreads();

  // per-wave GEMM helper: 4x16 rows, 1x16 col slice
  f32x4 acc[4];
  const int wfo = (wv * 64 + lane) * 8;   // weight fragment offset (t = wv)

  { // GEMM1: K=384
    float bv = b1[wcol0 + lrow];
#pragma unroll
    for (int mi = 0; mi < 4; ++mi) {
      f32x4 z; z[0] = bv; z[1] = bv; z[2] = bv; z[3] = bv;
      acc[mi] = z;
    }
#pragma unroll
    for (int s = 0; s < 12; ++s) {
      bf16x8 w0 = *(const bf16x8*)(pw1 + wfo + s * 4096);
      const unsigned short* ap =
          sm + (s >> 2) * PL + (s & 3) * 32 + lhi * 8;
#pragma unroll
      for (int mi = 0; mi < 4; ++mi) {
        bf16x8 a = *(const bf16x8*)(ap + (mi * 16 + lrow) * 136);
        acc[mi] = __builtin_amdgcn_mfma_f32_16x16x32_bf16(a, w0, acc[mi], 0, 0, 0);
      }
    }
  }
  __syncthreads();                          // P0 (x_src) dead -> H1
#pragma unroll
  for (int mi = 0; mi < 4; ++mi)
#pragma unroll
    for (int j = 0; j < 4; ++j)
      sm[(mi * 16 + lhi * 4 + j) * 136 + wcol0 + lrow] =
          f2bf(fmaxf(acc[mi][j], 0.f));
  __syncthreads();

  { // GEMM2: K=128
    float bv = b2[wcol0 + lrow];
#pragma unroll
    for (int mi = 0; mi < 4; ++mi) {
      f32x4 z; z[0] = bv; z[1] = bv; z[2] = bv; z[3] = bv;
      acc[mi] = z;
    }
#pragma unroll
    for (int s = 0; s < 4; ++s) {
      bf16x8 w0 = *(const bf16x8*)(pw2 + wfo + s * 4096);
      const unsigned short* ap = sm + s * 32 + lhi * 8;
#pragma unroll
      for (int mi = 0; mi < 4; ++mi) {
        bf16x8 a = *(const bf16x8*)(ap + (mi * 16 + lrow) * 136);
        acc[mi] = __builtin_amdgcn_mfma_f32_16x16x32_bf16(a, w0, acc[mi], 0, 0, 0);
      }
    }
  }
#pragma unroll
  for (int mi = 0; mi < 4; ++mi)            // H2 -> P1 (disjoint from H1)
#pragma unroll
    for (int j = 0; j < 4; ++j)
      sm[PL + (mi * 16 + lhi * 4 + j) * 136 + wcol0 + lrow] =
          f2bf(fmaxf(acc[mi][j], 0.f));
  __syncthreads();

  { // GEMM3: K=128
    float bv = b3[wcol0 + lrow];
#pragma unroll
    for (int mi = 0; mi < 4; ++mi) {
      f32x4 z; z[0] = bv; z[1] = bv; z[2] = bv; z[3] = bv;
      acc[mi] = z;
    }
#pragma unroll
    for (int s = 0; s < 4; ++s) {
      bf16x8 w0 = *(const bf16x8*)(pw3 + wfo + s * 4096);
      const unsigned short* ap = sm + PL + s * 32 + lhi * 8;
#pragma unroll
      for (int mi = 0; mi < 4; ++mi) {
        bf16x8 a = *(const bf16x8*)(ap + (mi * 16 + lrow) * 136);
        acc[mi] = __builtin_amdgcn_mfma_f32_16x16x32_bf16(a, w0, acc[mi], 0, 0, 0);
      }
    }
  }

  // LayerNorm reduce: 16-lane shuffle (16 cols) + LDS atomics merge 8 waves
  float ps[4], pq[4];
#pragma unroll
  for (int mi = 0; mi < 4; ++mi) {
    float s = 0.f, q2 = 0.f;
#pragma unroll
    for (int j = 0; j < 4; ++j) { /* per-j kept separate below */ }
    (void)s; (void)q2;
  }
#pragma unroll
  for (int j = 0; j < 4; ++j) { ps[j] = 0.f; pq[j] = 0.f; }
  float psj[4][1], pqj[4][1];
#pragma unroll
  for (int mi = 0; mi < 4; ++mi)
#pragma unroll
    for (int j = 0; j < 4; ++j) {
      float v = acc[mi][j];
      float s = v, q2 = v * v;
#pragma unroll
      for (int m = 1; m < 16; m <<= 1) {
        s += __shfl_xor(s, m);
        q2 += __shfl_xor(q2, m);
      }
      if (lrow == 0) {
        int rl = mi * 16 + lhi * 4 + j;
        atomicAdd(&red[rl * 2], s);
        atomicAdd(&red[rl * 2 + 1], q2);
      }
    }
  (void)psj; (void)pqj;
  __syncthreads();

  // normalize + residual (from LDS P2) + store
  float gv = gg[wcol0 + lrow];
  float bv = bb[wcol0 + lrow];
  const unsigned short* P2 = sm + 2 * PL;
  float* eaf = (float*)easlot;
#pragma unroll
  for (int mi = 0; mi < 4; ++mi)
#pragma unroll
    for (int j = 0; j < 4; ++j) {
      int rl = mi * 16 + lhi * 4 + j;
      long long e = block0 + rl;
      float mu = red[rl * 2] * (1.f / DD);
      float var = red[rl * 2 + 1] * (1.f / DD) - mu * mu;
      float rstd = rsqrtf(var + 1e-5f);
      int c = wcol0 + lrow;
      float nv = bf2f(P2[rl * 136 + c]) +
                 (acc[mi][j] - mu) * rstd * gv + bv;
      if (LAST) eaf[e * 128 + c] = nv;             // final f32, own slot
      else sm[rl * 136 + c] = f2bf(nv);            // stage in P0 (dead)
    }
  if (!LAST) {
    __syncthreads();
#pragma unroll
    for (int p = tid; p < 1024; p += 512) {
      int r = p >> 4, o = (p & 15) * 8;
      *(bf16x8*)(easlot + (long long)(block0 + r) * 256 + o) =
          *(const bf16x8*)(sm + r * 136 + o);
    }
  }
}

// ---------- node MLP: 32 nodes/block, CSR segment-sum, bf16 state ----------
template <bool LAST>
__global__ __launch_bounds__(256) void node_kernel(
    unsigned short* xbf, const unsigned short* __restrict__ easlot,
    float* xout,
    const int* __restrict__ off, const int* __restrict__ perm,
    const unsigned short* __restrict__ pw1,
    const unsigned short* __restrict__ pw2,
    const unsigned short* __restrict__ pw3,
    const float* __restrict__ b1, const float* __restrict__ b2,
    const float* __restrict__ b3, const float* __restrict__ gg,
    const float* __restrict__ bb) {
  __shared__ unsigned short sm[2 * 32 * 136];  // P0=x P1=agg
  __shared__ float red[64];
  constexpr int PL = 32 * 136;
  const int tid = threadIdx.x, lane = tid & 63, wv = tid >> 6;
  const int lrow = lane & 15, lhi = lane >> 4, wcol0 = wv * 32;
  const int block0 = blockIdx.x * 32;

  if (tid < 64) red[tid] = 0.f;

  { // stage A: x copy + f32-accumulated segment sum of ea
    int r = tid >> 3, c8 = tid & 7;
    int grow = block0 + r;
    int gr = grow < NNODES ? grow : NNODES - 1;
    const unsigned short* xs = xbf + (long long)gr * DD + c8 * 16;
    *(bf16x8*)(&sm[r * 136 + c8 * 16]) = *(const bf16x8*)xs;
    *(bf16x8*)(&sm[r * 136 + c8 * 16 + 8]) = *(const bf16x8*)(xs + 8);
    float a[16];
#pragma unroll
    for (int i = 0; i < 16; ++i) a[i] = 0.f;
    int p0 = off[gr], p1 = off[gr + 1];
    if (!LAST) {
      for (int p = p0; p < p1; ++p) {
        const unsigned short* ep = easlot + (long long)perm[p] * 256 + c8 * 16;
        bf16x8 u = *(const bf16x8*)ep;
        bf16x8 v = *(const bf16x8*)(ep + 8);
#pragma unroll
        for (int i = 0; i < 8; ++i) {
          a[i] += bf2f((unsigned short)u[i]);
          a[8 + i] += bf2f((unsigned short)v[i]);
        }
      }
    } else {
      const float* eaf = (const float*)easlot;
      for (int p = p0; p < p1; ++p) {
        const float* ep = eaf + (long long)perm[p] * 128 + c8 * 16;
        f32x4 u0 = *(const f32x4*)ep, u1 = *(const f32x4*)(ep + 4);
        f32x4 u2 = *(const f32x4*)(ep + 8), u3 = *(const f32x4*)(ep + 12);
#pragma unroll
        for (int i = 0; i < 4; ++i) {
          a[i] += u0[i]; a[4 + i] += u1[i]; a[8 + i] += u2[i]; a[12 + i] += u3[i];
        }
      }
    }
    bf16x8 o0, o1;
#pragma unroll
    for (int i = 0; i < 8; ++i) {
      o0[i] = (short)f2bf(a[i]);
      o1[i] = (short)f2bf(a[8 + i]);
    }
    *(bf16x8*)(&sm[PL + r * 136 + c8 * 16]) = o0;
    *(bf16x8*)(&sm[PL + r * 136 + c8 * 16 + 8]) = o1;
  }
  __syncthreads();

  f32x4 acc[2][2];
  gemm_step<8, 32, 2>(sm, pw1, b1, acc, lrow, lhi, lane, wv, wcol0);
  __syncthreads();
  relu_store<2>(acc, sm, lrow, lhi, wcol0);
  __syncthreads();
  gemm_step<4, 32, 2>(sm, pw2, b2, acc, lrow, lhi, lane, wv, wcol0);
  relu_store<2>(acc, sm + PL, lrow, lhi, wcol0);
  __syncthreads();
  gemm_step<4, 32, 2>(sm + PL, pw3, b3, acc, lrow, lhi, lane, wv, wcol0);

  float ps[2][4], pq[2][4];
#pragma unroll
  for (int mi = 0; mi < 2; ++mi)
#pragma unroll
    for (int j = 0; j < 4; ++j) {
      float a = acc[mi][0][j], b = acc[mi][1][j];
      ps[mi][j] = a + b;
      pq[mi][j] = a * a + b * b;
    }
#pragma unroll
  for (int m = 1; m < 16; m <<= 1)
#pragma unroll
    for (int mi = 0; mi < 2; ++mi)
#pragma unroll
      for (int j = 0; j < 4; ++j) {
        ps[mi][j] += __shfl_xor(ps[mi][j], m);
        pq[mi][j] += __shfl_xor(pq[mi][j], m);
      }
  if (lrow == 0)
#pragma unroll
    for (int mi = 0; mi < 2; ++mi)
#pragma unroll
      for (int j = 0; j < 4; ++j) {
        int rl = mi * 16 + lhi * 4 + j;
        atomicAdd(&red[rl * 2], ps[mi][j]);
        atomicAdd(&red[rl * 2 + 1], pq[mi][j]);
      }
  __syncthreads();

  float gv[2], bv[2];
  gv[0] = gg[wcol0 + lrow]; gv[1] = gg[wcol0 + 16 + lrow];
  bv[0] = bb[wcol0 + lrow]; bv[1] = bb[wcol0 + 16 + lrow];
#pragma unroll
  for (int mi = 0; mi < 2; ++mi)
#pragma unroll
    for (int j = 0; j < 4; ++j) {
      int rl = mi * 16 + lhi * 4 + j;
      int grow = block0 + rl;
      if (grow < NNODES) {
        float mu = red[rl * 2] * (1.f / DD);
        float var = red[rl * 2 + 1] * (1.f / DD) - mu * mu;
        float rstd = rsqrtf(var + 1e-5f);
#pragma unroll
        for (int ni = 0; ni < 2; ++ni) {
          int c = wcol0 + ni * 16 + lrow;
          float nv = bf2f(xbf[(long long)grow * DD + c]) +
                     (acc[mi][ni][j] - mu) * rstd * gv[ni] + bv[ni];
          if (LAST) xout[(long long)grow * DD + c] = nv;
          else sm[rl * 136 + c] = f2bf(nv);
        }
      }
    }
  if (!LAST) {
    __syncthreads();
#pragma unroll
    for (int p = tid; p < 512; p += 256) {
      int r = p >> 4, off2 = (p & 15) * 8;
      int grow = block0 + r;
      if (grow < NNODES)
        *(bf16x8*)(xbf + (long long)grow * DD + off2) =
            *(const bf16x8*)(sm + r * 136 + off2);
    }
  }
}

extern "C" void kernel_launch(void* const* d_in, const int* in_sizes, int n_in,
                              void* d_out, int out_size, void* d_ws, size_t ws_size,
                              hipStream_t stream) {
  const float* x  = (const float*)d_in[0];
  const int* ei   = (const int*)d_in[1];
  const float* ea = (const float*)d_in[2];
  const float* eW1 = (const float*)d_in[3];
  const float* eb1 = (const float*)d_in[4];
  const float* eW2 = (const float*)d_in[5];
  const float* eb2 = (const float*)d_in[6];
  const float* eW3 = (const float*)d_in[7];
  const float* eb3 = (const float*)d_in[8];
  const float* eg  = (const float*)d_in[9];
  const float* ebt = (const float*)d_in[10];
  const float* nW1 = (const float*)d_in[11];
  const float* nb1 = (const float*)d_in[12];
  const float* nW2 = (const float*)d_in[13];
  const float* nb2 = (const float*)d_in[14];
  const float* nW3 = (const float*)d_in[15];
  const float* nb3 = (const float*)d_in[16];
  const float* ng  = (const float*)d_in[17];
  const float* nbt = (const float*)d_in[18];

  float* xout = (float*)d_out;                               // final x f32
  unsigned short* easlot =
      (unsigned short*)(xout + (size_t)NNODES * DD);          // [E] 512B slots

  // workspace: packed weights | x_bf | cursor | off | perm
  unsigned short* pk_eW1 = (unsigned short*)d_ws;
  unsigned short* pk_eW2 = pk_eW1 + (size_t)L_ITERS * 384 * DD;
  unsigned short* pk_eW3 = pk_eW2 + (size_t)L_ITERS * DD * DD;
  unsigned short* pk_nW1 = pk_eW3 + (size_t)L_ITERS * DD * DD;
  unsigned short* pk_nW2 = pk_nW1 + (size_t)L_ITERS * 256 * DD;
  unsigned short* pk_nW3 = pk_nW2 + (size_t)L_ITERS * DD * DD;
  unsigned short* xbf = pk_nW3 + (size_t)L_ITERS * DD * DD;
  int* cursor = (int*)(xbf + (size_t)NNODES * DD);
  int* off    = cursor + NNODES;
  int* perm   = off + NNODES + 1;
  size_t need = (size_t)((char*)(perm + NEDGES) - (char*)d_ws);
  if (ws_size < need) return;

  pack_w_kernel<<<1024, 256, 0, stream>>>(eW1, pk_eW1, 384);
  pack_w_kernel<<<1024, 256, 0, stream>>>(eW2, pk_eW2, 128);
  pack_w_kernel<<<1024, 256, 0, stream>>>(eW3, pk_eW3, 128);
  pack_w_kernel<<<1024, 256, 0, stream>>>(nW1, pk_nW1, 256);
  pack_w_kernel<<<1024, 256, 0, stream>>>(nW2, pk_nW2, 128);
  pack_w_kernel<<<1024, 256, 0, stream>>>(nW3, pk_nW3, 128);

  cvt_kernel<<<1024, 256, 0, stream>>>(x, xbf, NNODES, 128);
  cvt_kernel<<<4096, 256, 0, stream>>>(ea, easlot, NEDGES, 256);

  hipMemsetAsync(cursor, 0, NNODES * sizeof(int), stream);
  hist_kernel<<<2048, 256, 0, stream>>>(ei, cursor);
  scan_kernel<<<1, 1024, 0, stream>>>(cursor, off, cursor);
  scatter_kernel<<<2048, 256, 0, stream>>>(ei, cursor, perm);

  for (int l = 0; l < L_ITERS; ++l) {
    if (l < L_ITERS - 1) {
      edge_kernel<false><<<NEDGES / 64, 512, 0, stream>>>(
          xbf, easlot, ei,
          pk_eW1 + (size_t)l * 384 * DD, pk_eW2 + (size_t)l * DD * DD,
          pk_eW3 + (size_t)l * DD * DD,
          eb1 + l * DD, eb2 + l * DD, eb3 + l * DD, eg + l * DD, ebt + l * DD);
      node_kernel<false><<<(NNODES + 31) / 32, 256, 0, stream>>>(
          xbf, easlot, xout, off, perm,
          pk_nW1 + (size_t)l * 256 * DD, pk_nW2 + (size_t)l * DD * DD,
          pk_nW3 + (size_t)l * DD * DD,
          nb1 + l * DD, nb2 + l * DD, nb3 + l * DD, ng + l * DD, nbt + l * DD);
    } else {
      edge_kernel<true><<<NEDGES / 64, 512, 0, stream>>>(
          xbf, easlot, ei,
          pk_eW1 + (size_t)l * 384 * DD, pk_eW2 + (size_t)l * DD * DD,
          pk_eW3 + (size_t)l * DD * DD,
          eb1 + l * DD, eb2 + l * DD, eb3 + l * DD, eg + l * DD, ebt + l * DD);
      node_kernel<true><<<(NNODES + 31) / 32, 256, 0, stream>>>(
          xbf, easlot, xout, off, perm,
          pk_nW1 + (size_t)l * 256 * DD, pk_nW2 + (size_t)l * DD * DD,
          pk_nW3 + (size_t)l * DD * DD,
          nb1 + l * DD, nb2 + l * DD, nb3 + l * DD, ng + l * DD, nbt + l * DD);
    }
  }
}

// Round 13
// 4498.730 us; speedup vs baseline: 1.4363x; 1.4363x over previous
//
#include <hip/hip_runtime.h>
#include <hip/hip_bf16.h>

#define L_ITERS 15
#define DD 128
#define NNODES 50000
#define NEDGES 800000

typedef __attribute__((ext_vector_type(4))) float f32x4;
typedef __attribute__((ext_vector_type(8))) short bf16x8;
typedef __attribute__((ext_vector_type(4))) short bf16x4;

// Native bf16 converts: compiler emits HW cvt (and fuses v_cvt_pk_bf16_f32).
static __device__ __forceinline__ unsigned short f2bf(float f) {
  union { __bf16 b; unsigned short u; } c;
  c.b = (__bf16)f;
  return c.u;
}
static __device__ __forceinline__ float bf2f(unsigned short h) {
  union { unsigned short u; __bf16 b; } c;
  c.u = h;
  return (float)c.b;
}

// Pack f32 weight [L][K][128] into MFMA B-fragment order (bf16):
// lane l of k-step s, n-frag t holds B[s*32 + (l>>4)*8 + j][t*16 + (l&15)], j=0..7
__global__ void pack_w_kernel(const float* __restrict__ src,
                              unsigned short* __restrict__ dst, int K) {
  int total = L_ITERS * K * DD;
  for (int i = blockIdx.x * blockDim.x + threadIdx.x; i < total;
       i += gridDim.x * blockDim.x) {
    int layer = i / (K * DD);
    int rem = i - layer * K * DD;
    int k = rem / DD, n = rem - (rem / DD) * DD;
    int s = k >> 5, hi = (k >> 3) & 3, j = k & 7;
    int t = n >> 4, lane = hi * 16 + (n & 15);
    dst[layer * K * DD + ((s * 8 + t) * 64 + lane) * 8 + j] = f2bf(src[i]);
  }
}

// f32 [rows][128] -> bf16 rows with dst row stride (shorts)
__global__ void cvt_kernel(const float* __restrict__ src,
                           unsigned short* __restrict__ dst,
                           int nrows, int dstride) {
  int total = nrows * 16;
  for (int p = blockIdx.x * blockDim.x + threadIdx.x; p < total;
       p += gridDim.x * blockDim.x) {
    int r = p >> 4, w = p & 15;
    const float* s = src + (long long)r * DD + w * 8;
    f32x4 a = *(const f32x4*)s, b = *(const f32x4*)(s + 4);
    bf16x8 o;
    o[0] = (short)f2bf(a[0]); o[1] = (short)f2bf(a[1]);
    o[2] = (short)f2bf(a[2]); o[3] = (short)f2bf(a[3]);
    o[4] = (short)f2bf(b[0]); o[5] = (short)f2bf(b[1]);
    o[6] = (short)f2bf(b[2]); o[7] = (short)f2bf(b[3]);
    *(bf16x8*)(dst + (long long)r * dstride + w * 8) = o;
  }
}

// ---------- CSR preprocessing (once per call) ----------
__global__ void hist_kernel(const int* __restrict__ ei, int* __restrict__ cnt) {
  for (int e = blockIdx.x * blockDim.x + threadIdx.x; e < NEDGES;
       e += gridDim.x * blockDim.x)
    atomicAdd(&cnt[ei[NEDGES + e]], 1);
}

__global__ __launch_bounds__(1024) void scan_kernel(const int* __restrict__ cnt,
                                                    int* __restrict__ off,
                                                    int* __restrict__ cursor) {
  __shared__ int buf[1024];
  __shared__ int base;
  if (threadIdx.x == 0) { base = 0; off[0] = 0; }
  __syncthreads();
  for (int start = 0; start < NNODES; start += 1024) {
    int i = start + threadIdx.x;
    int v = (i < NNODES) ? cnt[i] : 0;
    buf[threadIdx.x] = v;
    __syncthreads();
    for (int d = 1; d < 1024; d <<= 1) {
      int t = (threadIdx.x >= d) ? buf[threadIdx.x - d] : 0;
      __syncthreads();
      buf[threadIdx.x] += t;
      __syncthreads();
    }
    if (i < NNODES) {
      int incl = base + buf[threadIdx.x];
      off[i + 1] = incl;
      cursor[i] = incl - v;   // exclusive start
    }
    __syncthreads();
    if (threadIdx.x == 0) base += buf[1023];
    __syncthreads();
  }
}

__global__ void scatter_kernel(const int* __restrict__ ei, int* __restrict__ cursor,
                               int* __restrict__ perm) {
  for (int e = blockIdx.x * blockDim.x + threadIdx.x; e < NEDGES;
       e += gridDim.x * blockDim.x) {
    int p = atomicAdd(&cursor[ei[NEDGES + e]], 1);
    perm[p] = e;
  }
}

// ---------- GEMM pieces ----------
// A in LDS, plane-major [(NS+3)/4][ROWS][136] bf16. acc = A @ Wpacked + bias.
template <int NS, int ROWS, int MI>
static __device__ __forceinline__ void gemm_step(
    const unsigned short* A, const unsigned short* __restrict__ pw,
    const float* __restrict__ bias, f32x4 (&acc)[MI][2],
    int lrow, int lhi, int lane, int wv, int wcol0) {
  float bv0 = bias[wcol0 + lrow];
  float bv1 = bias[wcol0 + 16 + lrow];
#pragma unroll
  for (int mi = 0; mi < MI; ++mi) {
    f32x4 z0, z1;
    z0[0] = bv0; z0[1] = bv0; z0[2] = bv0; z0[3] = bv0;
    z1[0] = bv1; z1[1] = bv1; z1[2] = bv1; z1[3] = bv1;
    acc[mi][0] = z0; acc[mi][1] = z1;
  }
  const unsigned short* bp = pw + (wv * 2 * 64 + lane) * 8;
#pragma unroll
  for (int s = 0; s < NS; ++s) {
    bf16x8 w0 = *(const bf16x8*)(bp + s * 4096);
    bf16x8 w1 = *(const bf16x8*)(bp + s * 4096 + 512);
    const unsigned short* ap = A + (s >> 2) * (ROWS * 136) + (s & 3) * 32 + lhi * 8;
#pragma unroll
    for (int mi = 0; mi < MI; ++mi) {
      bf16x8 a = *(const bf16x8*)(ap + (mi * 16 + lrow) * 136);
      acc[mi][0] = __builtin_amdgcn_mfma_f32_16x16x32_bf16(a, w0, acc[mi][0], 0, 0, 0);
      acc[mi][1] = __builtin_amdgcn_mfma_f32_16x16x32_bf16(a, w1, acc[mi][1], 0, 0, 0);
    }
  }
}

template <int MI>
static __device__ __forceinline__ void relu_store(const f32x4 (&acc)[MI][2],
                                                  unsigned short* H,
                                                  int lrow, int lhi, int wcol0) {
#pragma unroll
  for (int mi = 0; mi < MI; ++mi)
#pragma unroll
    for (int ni = 0; ni < 2; ++ni)
#pragma unroll
      for (int j = 0; j < 4; ++j)
        H[(mi * 16 + lhi * 4 + j) * 136 + wcol0 + ni * 16 + lrow] =
            f2bf(fmaxf(acc[mi][ni][j], 0.f));
}

// ---------- edge MLP: 64 edges/block, 3 LDS planes, vector epilogue ----------
// easlot: [E] slots of 256 shorts (=512B). Iterations keep bf16 row in first
// 128 shorts; LAST writes the full slot as 128 f32 (the final output).
// Epilogue: acc -> F f32 [64][132] (dead P0+P1), 1/4-row per thread,
// f64 LN stats (higher accuracy than the f32 shuffle tree), 4 shuffles,
// direct coalesced global stores (piece p=q+4k).
template <bool LAST>
__global__ __launch_bounds__(256) void edge_kernel(
    const unsigned short* __restrict__ xbf, unsigned short* easlot,
    const int* __restrict__ ei,
    const unsigned short* __restrict__ pw1,
    const unsigned short* __restrict__ pw2,
    const unsigned short* __restrict__ pw3,
    const float* __restrict__ b1, const float* __restrict__ b2,
    const float* __restrict__ b3, const float* __restrict__ gg,
    const float* __restrict__ bb) {
  __shared__ unsigned short sm[3 * 64 * 136];  // P0=x_src P1=x_dst P2=ea
  constexpr int PL = 64 * 136;
  const int tid = threadIdx.x, lane = tid & 63, wv = tid >> 6;
  const int lrow = lane & 15, lhi = lane >> 4, wcol0 = wv * 32;
  const long long block0 = (long long)blockIdx.x * 64;  // NEDGES % 64 == 0

  { // stage A: pure 16B bf16 copies; 4 threads/row, 12 pieces each
    int r = tid >> 2, q = tid & 3;
    long long e = block0 + r;
    const unsigned short* s0 = xbf + (long long)ei[e] * DD;
    const unsigned short* s1 = xbf + (long long)ei[NEDGES + e] * DD;
    const unsigned short* s2 = easlot + e * 256;
#pragma unroll
    for (int k = 0; k < 12; ++k) {
      int w = q + 4 * k;
      int plane = w >> 4, off = (w & 15) * 8;
      const unsigned short* sp = (plane == 0) ? s0 : (plane == 1 ? s1 : s2);
      *(bf16x8*)(&sm[plane * PL + r * 136 + off]) = *(const bf16x8*)(sp + off);
    }
  }
  __syncthreads();

  f32x4 acc[4][2];
  gemm_step<12, 64, 4>(sm, pw1, b1, acc, lrow, lhi, lane, wv, wcol0);
  __syncthreads();                          // P0 (x_src) dead -> H1
  relu_store<4>(acc, sm, lrow, lhi, wcol0);
  __syncthreads();
  gemm_step<4, 64, 4>(sm, pw2, b2, acc, lrow, lhi, lane, wv, wcol0);
  relu_store<4>(acc, sm + PL, lrow, lhi, wcol0);   // P1 (x_dst) dead
  __syncthreads();
  gemm_step<4, 64, 4>(sm + PL, pw3, b3, acc, lrow, lhi, lane, wv, wcol0);
  __syncthreads();                          // all H2 (P1) reads done

  // acc -> F f32 [64][132] over P0+P1 (33792B <= 34816B); stride 132 keeps
  // the later b128 row reads at the 8-lane/bank-group floor.
  float* F = (float*)sm;
#pragma unroll
  for (int mi = 0; mi < 4; ++mi)
#pragma unroll
    for (int ni = 0; ni < 2; ++ni)
#pragma unroll
      for (int j = 0; j < 4; ++j)
        F[(mi * 16 + lhi * 4 + j) * 132 + wcol0 + ni * 16 + lrow] =
            acc[mi][ni][j];
  __syncthreads();

  // per-thread 1/4 row: r = tid>>2, thread q owns pieces p = q + 4k.
  // LN stats in f64: strictly more accurate than any f32 ordering, so the
  // result tracks the f32 reference to ~1e-7 (bf16 state noise dominates).
  const int r = tid >> 2, q = tid & 3;
  const long long e = block0 + r;
  const unsigned short* P2 = sm + 2 * PL;   // original ea bf16 (intact)
  float av[32];
  double s = 0.0, q2 = 0.0;
  if (!LAST) {
#pragma unroll
    for (int k = 0; k < 4; ++k) {           // piece = 16B = 8 bf16 cols
      int c0 = 8 * (q + 4 * k);
      f32x4 u0 = *(const f32x4*)(F + r * 132 + c0);
      f32x4 u1 = *(const f32x4*)(F + r * 132 + c0 + 4);
#pragma unroll
      for (int i = 0; i < 4; ++i) {
        double d0 = (double)u0[i], d1 = (double)u1[i];
        av[8 * k + i] = u0[i];     s += d0; q2 += d0 * d0;
        av[8 * k + 4 + i] = u1[i]; s += d1; q2 += d1 * d1;
      }
    }
  } else {
#pragma unroll
    for (int k = 0; k < 8; ++k) {           // piece = 16B = 4 f32 cols
      int c0 = 4 * (q + 4 * k);
      f32x4 u = *(const f32x4*)(F + r * 132 + c0);
#pragma unroll
      for (int i = 0; i < 4; ++i) {
        double d = (double)u[i];
        av[4 * k + i] = u[i]; s += d; q2 += d * d;
      }
    }
  }
  // butterfly over the 4 threads of this row (lanes differ by 1,2)
  s += __shfl_xor(s, 1);  s += __shfl_xor(s, 2);
  q2 += __shfl_xor(q2, 1); q2 += __shfl_xor(q2, 2);
  double mu_d = s * (1.0 / DD);
  double var_d = q2 * (1.0 / DD) - mu_d * mu_d;
  float mu = (float)mu_d;
  float rstd = rsqrtf((float)var_d + 1e-5f);

  // normalize + residual (from P2) + direct coalesced global store:
  // per instruction the 4 q-threads of each row cover 64B contiguous.
  if (!LAST) {
#pragma unroll
    for (int k = 0; k < 4; ++k) {
      int c0 = 8 * (q + 4 * k);
      bf16x8 rv = *(const bf16x8*)(P2 + r * 136 + c0);
      f32x4 g0 = *(const f32x4*)(gg + c0), g1 = *(const f32x4*)(gg + c0 + 4);
      f32x4 t0 = *(const f32x4*)(bb + c0), t1 = *(const f32x4*)(bb + c0 + 4);
      bf16x8 o;
#pragma unroll
      for (int i = 0; i < 4; ++i) {
        o[i] = (short)f2bf(bf2f((unsigned short)rv[i]) +
                           (av[8 * k + i] - mu) * rstd * g0[i] + t0[i]);
        o[4 + i] = (short)f2bf(bf2f((unsigned short)rv[4 + i]) +
                               (av[8 * k + 4 + i] - mu) * rstd * g1[i] + t1[i]);
      }
      *(bf16x8*)(easlot + e * 256 + c0) = o;
    }
  } else {
    float* eaf = (float*)easlot;
#pragma unroll
    for (int k = 0; k < 8; ++k) {
      int c0 = 4 * (q + 4 * k);
      bf16x4 rv = *(const bf16x4*)(P2 + r * 136 + c0);
      f32x4 g0 = *(const f32x4*)(gg + c0);
      f32x4 t0 = *(const f32x4*)(bb + c0);
      f32x4 o;
#pragma unroll
      for (int i = 0; i < 4; ++i)
        o[i] = bf2f((unsigned short)rv[i]) +
               (av[4 * k + i] - mu) * rstd * g0[i] + t0[i];
      *(f32x4*)(eaf + e * 128 + c0) = o;
    }
  }
}

// ---------- node MLP: 32 nodes/block, CSR segment-sum, bf16 state ----------
template <bool LAST>
__global__ __launch_bounds__(256) void node_kernel(
    unsigned short* xbf, const unsigned short* __restrict__ easlot,
    float* xout,
    const int* __restrict__ off, const int* __restrict__ perm,
    const unsigned short* __restrict__ pw1,
    const unsigned short* __restrict__ pw2,
    const unsigned short* __restrict__ pw3,
    const float* __restrict__ b1, const float* __restrict__ b2,
    const float* __restrict__ b3, const float* __restrict__ gg,
    const float* __restrict__ bb) {
  __shared__ unsigned short sm[2 * 32 * 136];  // P0=x P1=agg
  __shared__ float red[64];
  constexpr int PL = 32 * 136;
  const int tid = threadIdx.x, lane = tid & 63, wv = tid >> 6;
  const int lrow = lane & 15, lhi = lane >> 4, wcol0 = wv * 32;
  const int block0 = blockIdx.x * 32;

  if (tid < 64) red[tid] = 0.f;

  { // stage A: x copy + f32-accumulated segment sum of ea
    int r = tid >> 3, c8 = tid & 7;
    int grow = block0 + r;
    int gr = grow < NNODES ? grow : NNODES - 1;
    const unsigned short* xs = xbf + (long long)gr * DD + c8 * 16;
    *(bf16x8*)(&sm[r * 136 + c8 * 16]) = *(const bf16x8*)xs;
    *(bf16x8*)(&sm[r * 136 + c8 * 16 + 8]) = *(const bf16x8*)(xs + 8);
    float a[16];
#pragma unroll
    for (int i = 0; i < 16; ++i) a[i] = 0.f;
    int p0 = off[gr], p1 = off[gr + 1];
    if (!LAST) {
      for (int p = p0; p < p1; ++p) {
        const unsigned short* ep = easlot + (long long)perm[p] * 256 + c8 * 16;
        bf16x8 u = *(const bf16x8*)ep;
        bf16x8 v = *(const bf16x8*)(ep + 8);
#pragma unroll
        for (int i = 0; i < 8; ++i) {
          a[i] += bf2f((unsigned short)u[i]);
          a[8 + i] += bf2f((unsigned short)v[i]);
        }
      }
    } else {
      const float* eaf = (const float*)easlot;
      for (int p = p0; p < p1; ++p) {
        const float* ep = eaf + (long long)perm[p] * 128 + c8 * 16;
        f32x4 u0 = *(const f32x4*)ep, u1 = *(const f32x4*)(ep + 4);
        f32x4 u2 = *(const f32x4*)(ep + 8), u3 = *(const f32x4*)(ep + 12);
#pragma unroll
        for (int i = 0; i < 4; ++i) {
          a[i] += u0[i]; a[4 + i] += u1[i]; a[8 + i] += u2[i]; a[12 + i] += u3[i];
        }
      }
    }
    bf16x8 o0, o1;
#pragma unroll
    for (int i = 0; i < 8; ++i) {
      o0[i] = (short)f2bf(a[i]);
      o1[i] = (short)f2bf(a[8 + i]);
    }
    *(bf16x8*)(&sm[PL + r * 136 + c8 * 16]) = o0;
    *(bf16x8*)(&sm[PL + r * 136 + c8 * 16 + 8]) = o1;
  }
  __syncthreads();

  f32x4 acc[2][2];
  gemm_step<8, 32, 2>(sm, pw1, b1, acc, lrow, lhi, lane, wv, wcol0);
  __syncthreads();
  relu_store<2>(acc, sm, lrow, lhi, wcol0);
  __syncthreads();
  gemm_step<4, 32, 2>(sm, pw2, b2, acc, lrow, lhi, lane, wv, wcol0);
  relu_store<2>(acc, sm + PL, lrow, lhi, wcol0);
  __syncthreads();
  gemm_step<4, 32, 2>(sm + PL, pw3, b3, acc, lrow, lhi, lane, wv, wcol0);

  float ps[2][4], pq[2][4];
#pragma unroll
  for (int mi = 0; mi < 2; ++mi)
#pragma unroll
    for (int j = 0; j < 4; ++j) {
      float a = acc[mi][0][j], b = acc[mi][1][j];
      ps[mi][j] = a + b;
      pq[mi][j] = a * a + b * b;
    }
#pragma unroll
  for (int m = 1; m < 16; m <<= 1)
#pragma unroll
    for (int mi = 0; mi < 2; ++mi)
#pragma unroll
      for (int j = 0; j < 4; ++j) {
        ps[mi][j] += __shfl_xor(ps[mi][j], m);
        pq[mi][j] += __shfl_xor(pq[mi][j], m);
      }
  if (lrow == 0)
#pragma unroll
    for (int mi = 0; mi < 2; ++mi)
#pragma unroll
      for (int j = 0; j < 4; ++j) {
        int rl = mi * 16 + lhi * 4 + j;
        atomicAdd(&red[rl * 2], ps[mi][j]);
        atomicAdd(&red[rl * 2 + 1], pq[mi][j]);
      }
  __syncthreads();

  float gv[2], bv[2];
  gv[0] = gg[wcol0 + lrow]; gv[1] = gg[wcol0 + 16 + lrow];
  bv[0] = bb[wcol0 + lrow]; bv[1] = bb[wcol0 + 16 + lrow];
#pragma unroll
  for (int mi = 0; mi < 2; ++mi)
#pragma unroll
    for (int j = 0; j < 4; ++j) {
      int rl = mi * 16 + lhi * 4 + j;
      int grow = block0 + rl;
      if (grow < NNODES) {
        float mu = red[rl * 2] * (1.f / DD);
        float var = red[rl * 2 + 1] * (1.f / DD) - mu * mu;
        float rstd = rsqrtf(var + 1e-5f);
#pragma unroll
        for (int ni = 0; ni < 2; ++ni) {
          int c = wcol0 + ni * 16 + lrow;
          float nv = bf2f(xbf[(long long)grow * DD + c]) +
                     (acc[mi][ni][j] - mu) * rstd * gv[ni] + bv[ni];
          if (LAST) xout[(long long)grow * DD + c] = nv;
          else sm[rl * 136 + c] = f2bf(nv);
        }
      }
    }
  if (!LAST) {
    __syncthreads();
#pragma unroll
    for (int p = tid; p < 512; p += 256) {
      int r = p >> 4, off2 = (p & 15) * 8;
      int grow = block0 + r;
      if (grow < NNODES)
        *(bf16x8*)(xbf + (long long)grow * DD + off2) =
            *(const bf16x8*)(sm + r * 136 + off2);
    }
  }
}

extern "C" void kernel_launch(void* const* d_in, const int* in_sizes, int n_in,
                              void* d_out, int out_size, void* d_ws, size_t ws_size,
                              hipStream_t stream) {
  const float* x  = (const float*)d_in[0];
  const int* ei   = (const int*)d_in[1];
  const float* ea = (const float*)d_in[2];
  const float* eW1 = (const float*)d_in[3];
  const float* eb1 = (const float*)d_in[4];
  const float* eW2 = (const float*)d_in[5];
  const float* eb2 = (const float*)d_in[6];
  const float* eW3 = (const float*)d_in[7];
  const float* eb3 = (const float*)d_in[8];
  const float* eg  = (const float*)d_in[9];
  const float* ebt = (const float*)d_in[10];
  const float* nW1 = (const float*)d_in[11];
  const float* nb1 = (const float*)d_in[12];
  const float* nW2 = (const float*)d_in[13];
  const float* nb2 = (const float*)d_in[14];
  const float* nW3 = (const float*)d_in[15];
  const float* nb3 = (const float*)d_in[16];
  const float* ng  = (const float*)d_in[17];
  const float* nbt = (const float*)d_in[18];

  float* xout = (float*)d_out;                               // final x f32
  unsigned short* easlot =
      (unsigned short*)(xout + (size_t)NNODES * DD);          // [E] 512B slots

  // workspace: packed weights | x_bf | cursor | off | perm
  unsigned short* pk_eW1 = (unsigned short*)d_ws;
  unsigned short* pk_eW2 = pk_eW1 + (size_t)L_ITERS * 384 * DD;
  unsigned short* pk_eW3 = pk_eW2 + (size_t)L_ITERS * DD * DD;
  unsigned short* pk_nW1 = pk_eW3 + (size_t)L_ITERS * DD * DD;
  unsigned short* pk_nW2 = pk_nW1 + (size_t)L_ITERS * 256 * DD;
  unsigned short* pk_nW3 = pk_nW2 + (size_t)L_ITERS * DD * DD;
  unsigned short* xbf = pk_nW3 + (size_t)L_ITERS * DD * DD;
  int* cursor = (int*)(xbf + (size_t)NNODES * DD);
  int* off    = cursor + NNODES;
  int* perm   = off + NNODES + 1;
  size_t need = (size_t)((char*)(perm + NEDGES) - (char*)d_ws);
  if (ws_size < need) return;

  pack_w_kernel<<<1024, 256, 0, stream>>>(eW1, pk_eW1, 384);
  pack_w_kernel<<<1024, 256, 0, stream>>>(eW2, pk_eW2, 128);
  pack_w_kernel<<<1024, 256, 0, stream>>>(eW3, pk_eW3, 128);
  pack_w_kernel<<<1024, 256, 0, stream>>>(nW1, pk_nW1, 256);
  pack_w_kernel<<<1024, 256, 0, stream>>>(nW2, pk_nW2, 128);
  pack_w_kernel<<<1024, 256, 0, stream>>>(nW3, pk_nW3, 128);

  cvt_kernel<<<1024, 256, 0, stream>>>(x, xbf, NNODES, 128);
  cvt_kernel<<<4096, 256, 0, stream>>>(ea, easlot, NEDGES, 256);

  hipMemsetAsync(cursor, 0, NNODES * sizeof(int), stream);
  hist_kernel<<<2048, 256, 0, stream>>>(ei, cursor);
  scan_kernel<<<1, 1024, 0, stream>>>(cursor, off, cursor);
  scatter_kernel<<<2048, 256, 0, stream>>>(ei, cursor, perm);

  for (int l = 0; l < L_ITERS; ++l) {
    if (l < L_ITERS - 1) {
      edge_kernel<false><<<NEDGES / 64, 256, 0, stream>>>(
          xbf, easlot, ei,
          pk_eW1 + (size_t)l * 384 * DD, pk_eW2 + (size_t)l * DD * DD,
          pk_eW3 + (size_t)l * DD * DD,
          eb1 + l * DD, eb2 + l * DD, eb3 + l * DD, eg + l * DD, ebt + l * DD);
      node_kernel<false><<<(NNODES + 31) / 32, 256, 0, stream>>>(
          xbf, easlot, xout, off, perm,
          pk_nW1 + (size_t)l * 256 * DD, pk_nW2 + (size_t)l * DD * DD,
          pk_nW3 + (size_t)l * DD * DD,
          nb1 + l * DD, nb2 + l * DD, nb3 + l * DD, ng + l * DD, nbt + l * DD);
    } else {
      edge_kernel<true><<<NEDGES / 64, 256, 0, stream>>>(
          xbf, easlot, ei,
          pk_eW1 + (size_t)l * 384 * DD, pk_eW2 + (size_t)l * DD * DD,
          pk_eW3 + (size_t)l * DD * DD,
          eb1 + l * DD, eb2 + l * DD, eb3 + l * DD, eg + l * DD, ebt + l * DD);
      node_kernel<true><<<(NNODES + 31) / 32, 256, 0, stream>>>(
          xbf, easlot, xout, off, perm,
          pk_nW1 + (size_t)l * 256 * DD, pk_nW2 + (size_t)l * DD * DD,
          pk_nW3 + (size_t)l * DD * DD,
          nb1 + l * DD, nb2 + l * DD, nb3 + l * DD, ng + l * DD, nbt + l * DD);
    }
  }
}

// Round 14
// 4485.478 us; speedup vs baseline: 1.4405x; 1.0030x over previous
//
#include <hip/hip_runtime.h>
#include <hip/hip_bf16.h>

#define L_ITERS 15
#define DD 128
#define NNODES 50000
#define NEDGES 800000

typedef __attribute__((ext_vector_type(4))) float f32x4;
typedef __attribute__((ext_vector_type(8))) short bf16x8;
typedef __attribute__((ext_vector_type(4))) short bf16x4;

// Native bf16 converts: compiler emits HW cvt (and fuses v_cvt_pk_bf16_f32).
static __device__ __forceinline__ unsigned short f2bf(float f) {
  union { __bf16 b; unsigned short u; } c;
  c.b = (__bf16)f;
  return c.u;
}
static __device__ __forceinline__ float bf2f(unsigned short h) {
  union { unsigned short u; __bf16 b; } c;
  c.u = h;
  return (float)c.b;
}

// Pack f32 weight [L][K][128] into MFMA B-fragment order (bf16):
// lane l of k-step s, n-frag t holds B[s*32 + (l>>4)*8 + j][t*16 + (l&15)], j=0..7
__global__ void pack_w_kernel(const float* __restrict__ src,
                              unsigned short* __restrict__ dst, int K) {
  int total = L_ITERS * K * DD;
  for (int i = blockIdx.x * blockDim.x + threadIdx.x; i < total;
       i += gridDim.x * blockDim.x) {
    int layer = i / (K * DD);
    int rem = i - layer * K * DD;
    int k = rem / DD, n = rem - (rem / DD) * DD;
    int s = k >> 5, hi = (k >> 3) & 3, j = k & 7;
    int t = n >> 4, lane = hi * 16 + (n & 15);
    dst[layer * K * DD + ((s * 8 + t) * 64 + lane) * 8 + j] = f2bf(src[i]);
  }
}

// f32 [rows][128] -> bf16 rows with dst row stride (shorts)
__global__ void cvt_kernel(const float* __restrict__ src,
                           unsigned short* __restrict__ dst,
                           int nrows, int dstride) {
  int total = nrows * 16;
  for (int p = blockIdx.x * blockDim.x + threadIdx.x; p < total;
       p += gridDim.x * blockDim.x) {
    int r = p >> 4, w = p & 15;
    const float* s = src + (long long)r * DD + w * 8;
    f32x4 a = *(const f32x4*)s, b = *(const f32x4*)(s + 4);
    bf16x8 o;
    o[0] = (short)f2bf(a[0]); o[1] = (short)f2bf(a[1]);
    o[2] = (short)f2bf(a[2]); o[3] = (short)f2bf(a[3]);
    o[4] = (short)f2bf(b[0]); o[5] = (short)f2bf(b[1]);
    o[6] = (short)f2bf(b[2]); o[7] = (short)f2bf(b[3]);
    *(bf16x8*)(dst + (long long)r * dstride + w * 8) = o;
  }
}

// ---------- CSR preprocessing (once per call) ----------
__global__ void hist_kernel(const int* __restrict__ ei, int* __restrict__ cnt) {
  for (int e = blockIdx.x * blockDim.x + threadIdx.x; e < NEDGES;
       e += gridDim.x * blockDim.x)
    atomicAdd(&cnt[ei[NEDGES + e]], 1);
}

__global__ __launch_bounds__(1024) void scan_kernel(const int* __restrict__ cnt,
                                                    int* __restrict__ off,
                                                    int* __restrict__ cursor) {
  __shared__ int buf[1024];
  __shared__ int base;
  if (threadIdx.x == 0) { base = 0; off[0] = 0; }
  __syncthreads();
  for (int start = 0; start < NNODES; start += 1024) {
    int i = start + threadIdx.x;
    int v = (i < NNODES) ? cnt[i] : 0;
    buf[threadIdx.x] = v;
    __syncthreads();
    for (int d = 1; d < 1024; d <<= 1) {
      int t = (threadIdx.x >= d) ? buf[threadIdx.x - d] : 0;
      __syncthreads();
      buf[threadIdx.x] += t;
      __syncthreads();
    }
    if (i < NNODES) {
      int incl = base + buf[threadIdx.x];
      off[i + 1] = incl;
      cursor[i] = incl - v;   // exclusive start
    }
    __syncthreads();
    if (threadIdx.x == 0) base += buf[1023];
    __syncthreads();
  }
}

__global__ void scatter_kernel(const int* __restrict__ ei, int* __restrict__ cursor,
                               int* __restrict__ perm) {
  for (int e = blockIdx.x * blockDim.x + threadIdx.x; e < NEDGES;
       e += gridDim.x * blockDim.x) {
    int p = atomicAdd(&cursor[ei[NEDGES + e]], 1);
    perm[p] = e;
  }
}

// ---------- GEMM pieces ----------
// A in LDS, plane-major [(NS+3)/4][ROWS][136] bf16. acc = A @ Wpacked + bias.
template <int NS, int ROWS, int MI>
static __device__ __forceinline__ void gemm_step(
    const unsigned short* A, const unsigned short* __restrict__ pw,
    const float* __restrict__ bias, f32x4 (&acc)[MI][2],
    int lrow, int lhi, int lane, int wv, int wcol0) {
  float bv0 = bias[wcol0 + lrow];
  float bv1 = bias[wcol0 + 16 + lrow];
#pragma unroll
  for (int mi = 0; mi < MI; ++mi) {
    f32x4 z0, z1;
    z0[0] = bv0; z0[1] = bv0; z0[2] = bv0; z0[3] = bv0;
    z1[0] = bv1; z1[1] = bv1; z1[2] = bv1; z1[3] = bv1;
    acc[mi][0] = z0; acc[mi][1] = z1;
  }
  const unsigned short* bp = pw + (wv * 2 * 64 + lane) * 8;
#pragma unroll
  for (int s = 0; s < NS; ++s) {
    bf16x8 w0 = *(const bf16x8*)(bp + s * 4096);
    bf16x8 w1 = *(const bf16x8*)(bp + s * 4096 + 512);
    const unsigned short* ap = A + (s >> 2) * (ROWS * 136) + (s & 3) * 32 + lhi * 8;
#pragma unroll
    for (int mi = 0; mi < MI; ++mi) {
      bf16x8 a = *(const bf16x8*)(ap + (mi * 16 + lrow) * 136);
      acc[mi][0] = __builtin_amdgcn_mfma_f32_16x16x32_bf16(a, w0, acc[mi][0], 0, 0, 0);
      acc[mi][1] = __builtin_amdgcn_mfma_f32_16x16x32_bf16(a, w1, acc[mi][1], 0, 0, 0);
    }
  }
}

template <int MI>
static __device__ __forceinline__ void relu_store(const f32x4 (&acc)[MI][2],
                                                  unsigned short* H,
                                                  int lrow, int lhi, int wcol0) {
#pragma unroll
  for (int mi = 0; mi < MI; ++mi)
#pragma unroll
    for (int ni = 0; ni < 2; ++ni)
#pragma unroll
      for (int j = 0; j < 4; ++j)
        H[(mi * 16 + lhi * 4 + j) * 136 + wcol0 + ni * 16 + lrow] =
            f2bf(fmaxf(acc[mi][ni][j], 0.f));
}

// ---------- edge MLP: 64 edges/block, 3 LDS planes, vector epilogue ----------
// easlot: [E] slots of 256 shorts (=512B). Iterations keep bf16 row in first
// 128 shorts; LAST writes the full slot as 128 f32 (the final output).
// Epilogue: acc -> F f32 [64][132] (dead P0+P1); 8 threads/row x 2 row-passes,
// f64 LN stats + 3-shuffle butterfly; every store instruction covers a full
// 128B line per row (no write amplification — rounds 6/13 lesson).
template <bool LAST>
__global__ __launch_bounds__(256) void edge_kernel(
    const unsigned short* __restrict__ xbf, unsigned short* easlot,
    const int* __restrict__ ei,
    const unsigned short* __restrict__ pw1,
    const unsigned short* __restrict__ pw2,
    const unsigned short* __restrict__ pw3,
    const float* __restrict__ b1, const float* __restrict__ b2,
    const float* __restrict__ b3, const float* __restrict__ gg,
    const float* __restrict__ bb) {
  __shared__ unsigned short sm[3 * 64 * 136];  // P0=x_src P1=x_dst P2=ea
  constexpr int PL = 64 * 136;
  const int tid = threadIdx.x, lane = tid & 63, wv = tid >> 6;
  const int lrow = lane & 15, lhi = lane >> 4, wcol0 = wv * 32;
  const long long block0 = (long long)blockIdx.x * 64;  // NEDGES % 64 == 0

  { // stage A: pure 16B bf16 copies; 4 threads/row, 12 pieces each
    int r = tid >> 2, q = tid & 3;
    long long e = block0 + r;
    const unsigned short* s0 = xbf + (long long)ei[e] * DD;
    const unsigned short* s1 = xbf + (long long)ei[NEDGES + e] * DD;
    const unsigned short* s2 = easlot + e * 256;
#pragma unroll
    for (int k = 0; k < 12; ++k) {
      int w = q + 4 * k;
      int plane = w >> 4, off = (w & 15) * 8;
      const unsigned short* sp = (plane == 0) ? s0 : (plane == 1 ? s1 : s2);
      *(bf16x8*)(&sm[plane * PL + r * 136 + off]) = *(const bf16x8*)(sp + off);
    }
  }
  __syncthreads();

  f32x4 acc[4][2];
  gemm_step<12, 64, 4>(sm, pw1, b1, acc, lrow, lhi, lane, wv, wcol0);
  __syncthreads();                          // P0 (x_src) dead -> H1
  relu_store<4>(acc, sm, lrow, lhi, wcol0);
  __syncthreads();
  gemm_step<4, 64, 4>(sm, pw2, b2, acc, lrow, lhi, lane, wv, wcol0);
  relu_store<4>(acc, sm + PL, lrow, lhi, wcol0);   // P1 (x_dst) dead
  __syncthreads();
  gemm_step<4, 64, 4>(sm + PL, pw3, b3, acc, lrow, lhi, lane, wv, wcol0);
  __syncthreads();                          // all H2 (P1) reads done

  // acc -> F f32 [64][132] over P0+P1 (33792B <= 34816B); stride 132 keeps
  // the later b128 row reads at the 8-lane/bank-group floor.
  float* F = (float*)sm;
#pragma unroll
  for (int mi = 0; mi < 4; ++mi)
#pragma unroll
    for (int ni = 0; ni < 2; ++ni)
#pragma unroll
      for (int j = 0; j < 4; ++j)
        F[(mi * 16 + lhi * 4 + j) * 132 + wcol0 + ni * 16 + lrow] =
            acc[mi][ni][j];
  __syncthreads();

  // 8 threads/row, 2 row passes. Thread q of row r owns cols so that each
  // store instruction writes 8 threads x 16B = 128B aligned per row.
  const int r0 = tid >> 3, q = tid & 7;
  const unsigned short* P2 = sm + 2 * PL;   // original ea bf16 (intact)
  float* eaf = (float*)easlot;
#pragma unroll
  for (int pass = 0; pass < 2; ++pass) {
    const int r = r0 + pass * 32;
    const long long e = block0 + r;
    float av[16];
    double s = 0.0, q2 = 0.0;
    if (!LAST) {
#pragma unroll
      for (int k = 0; k < 2; ++k) {         // 8 cols per k: c0 = 8q + 64k
        int c0 = 8 * q + 64 * k;
        f32x4 u0 = *(const f32x4*)(F + r * 132 + c0);
        f32x4 u1 = *(const f32x4*)(F + r * 132 + c0 + 4);
#pragma unroll
        for (int i = 0; i < 4; ++i) {
          double d0 = (double)u0[i], d1 = (double)u1[i];
          av[8 * k + i] = u0[i];     s += d0; q2 += d0 * d0;
          av[8 * k + 4 + i] = u1[i]; s += d1; q2 += d1 * d1;
        }
      }
    } else {
#pragma unroll
      for (int k = 0; k < 4; ++k) {         // 4 cols per k: c0 = 4q + 32k
        int c0 = 4 * q + 32 * k;
        f32x4 u = *(const f32x4*)(F + r * 132 + c0);
#pragma unroll
        for (int i = 0; i < 4; ++i) {
          double d = (double)u[i];
          av[4 * k + i] = u[i]; s += d; q2 += d * d;
        }
      }
    }
    // butterfly over the 8 threads of this row (lanes differ by 1,2,4)
    s += __shfl_xor(s, 1);  s += __shfl_xor(s, 2);  s += __shfl_xor(s, 4);
    q2 += __shfl_xor(q2, 1); q2 += __shfl_xor(q2, 2); q2 += __shfl_xor(q2, 4);
    double mu_d = s * (1.0 / DD);
    double var_d = q2 * (1.0 / DD) - mu_d * mu_d;
    float mu = (float)mu_d;
    float rstd = rsqrtf((float)var_d + 1e-5f);

    if (!LAST) {
#pragma unroll
      for (int k = 0; k < 2; ++k) {
        int c0 = 8 * q + 64 * k;
        bf16x8 rv = *(const bf16x8*)(P2 + r * 136 + c0);
        f32x4 g0 = *(const f32x4*)(gg + c0), g1 = *(const f32x4*)(gg + c0 + 4);
        f32x4 t0 = *(const f32x4*)(bb + c0), t1 = *(const f32x4*)(bb + c0 + 4);
        bf16x8 o;
#pragma unroll
        for (int i = 0; i < 4; ++i) {
          o[i] = (short)f2bf(bf2f((unsigned short)rv[i]) +
                             (av[8 * k + i] - mu) * rstd * g0[i] + t0[i]);
          o[4 + i] = (short)f2bf(bf2f((unsigned short)rv[4 + i]) +
                                 (av[8 * k + 4 + i] - mu) * rstd * g1[i] + t1[i]);
        }
        *(bf16x8*)(easlot + e * 256 + c0) = o;   // 8 threads -> 128B line
      }
    } else {
#pragma unroll
      for (int k = 0; k < 4; ++k) {
        int c0 = 4 * q + 32 * k;
        bf16x4 rv = *(const bf16x4*)(P2 + r * 136 + c0);
        f32x4 g0 = *(const f32x4*)(gg + c0);
        f32x4 t0 = *(const f32x4*)(bb + c0);
        f32x4 o;
#pragma unroll
        for (int i = 0; i < 4; ++i)
          o[i] = bf2f((unsigned short)rv[i]) +
                 (av[4 * k + i] - mu) * rstd * g0[i] + t0[i];
        *(f32x4*)(eaf + e * 128 + c0) = o;       // 8 threads -> 128B line
      }
    }
  }
}

// ---------- node MLP: 32 nodes/block, CSR segment-sum, bf16 state ----------
template <bool LAST>
__global__ __launch_bounds__(256) void node_kernel(
    unsigned short* xbf, const unsigned short* __restrict__ easlot,
    float* xout,
    const int* __restrict__ off, const int* __restrict__ perm,
    const unsigned short* __restrict__ pw1,
    const unsigned short* __restrict__ pw2,
    const unsigned short* __restrict__ pw3,
    const float* __restrict__ b1, const float* __restrict__ b2,
    const float* __restrict__ b3, const float* __restrict__ gg,
    const float* __restrict__ bb) {
  __shared__ unsigned short sm[2 * 32 * 136];  // P0=x P1=agg
  __shared__ float red[64];
  constexpr int PL = 32 * 136;
  const int tid = threadIdx.x, lane = tid & 63, wv = tid >> 6;
  const int lrow = lane & 15, lhi = lane >> 4, wcol0 = wv * 32;
  const int block0 = blockIdx.x * 32;

  if (tid < 64) red[tid] = 0.f;

  { // stage A: x copy + f32-accumulated segment sum of ea
    int r = tid >> 3, c8 = tid & 7;
    int grow = block0 + r;
    int gr = grow < NNODES ? grow : NNODES - 1;
    const unsigned short* xs = xbf + (long long)gr * DD + c8 * 16;
    *(bf16x8*)(&sm[r * 136 + c8 * 16]) = *(const bf16x8*)xs;
    *(bf16x8*)(&sm[r * 136 + c8 * 16 + 8]) = *(const bf16x8*)(xs + 8);
    float a[16];
#pragma unroll
    for (int i = 0; i < 16; ++i) a[i] = 0.f;
    int p0 = off[gr], p1 = off[gr + 1];
    if (!LAST) {
      for (int p = p0; p < p1; ++p) {
        const unsigned short* ep = easlot + (long long)perm[p] * 256 + c8 * 16;
        bf16x8 u = *(const bf16x8*)ep;
        bf16x8 v = *(const bf16x8*)(ep + 8);
#pragma unroll
        for (int i = 0; i < 8; ++i) {
          a[i] += bf2f((unsigned short)u[i]);
          a[8 + i] += bf2f((unsigned short)v[i]);
        }
      }
    } else {
      const float* eaf = (const float*)easlot;
      for (int p = p0; p < p1; ++p) {
        const float* ep = eaf + (long long)perm[p] * 128 + c8 * 16;
        f32x4 u0 = *(const f32x4*)ep, u1 = *(const f32x4*)(ep + 4);
        f32x4 u2 = *(const f32x4*)(ep + 8), u3 = *(const f32x4*)(ep + 12);
#pragma unroll
        for (int i = 0; i < 4; ++i) {
          a[i] += u0[i]; a[4 + i] += u1[i]; a[8 + i] += u2[i]; a[12 + i] += u3[i];
        }
      }
    }
    bf16x8 o0, o1;
#pragma unroll
    for (int i = 0; i < 8; ++i) {
      o0[i] = (short)f2bf(a[i]);
      o1[i] = (short)f2bf(a[8 + i]);
    }
    *(bf16x8*)(&sm[PL + r * 136 + c8 * 16]) = o0;
    *(bf16x8*)(&sm[PL + r * 136 + c8 * 16 + 8]) = o1;
  }
  __syncthreads();

  f32x4 acc[2][2];
  gemm_step<8, 32, 2>(sm, pw1, b1, acc, lrow, lhi, lane, wv, wcol0);
  __syncthreads();
  relu_store<2>(acc, sm, lrow, lhi, wcol0);
  __syncthreads();
  gemm_step<4, 32, 2>(sm, pw2, b2, acc, lrow, lhi, lane, wv, wcol0);
  relu_store<2>(acc, sm + PL, lrow, lhi, wcol0);
  __syncthreads();
  gemm_step<4, 32, 2>(sm + PL, pw3, b3, acc, lrow, lhi, lane, wv, wcol0);

  float ps[2][4], pq[2][4];
#pragma unroll
  for (int mi = 0; mi < 2; ++mi)
#pragma unroll
    for (int j = 0; j < 4; ++j) {
      float a = acc[mi][0][j], b = acc[mi][1][j];
      ps[mi][j] = a + b;
      pq[mi][j] = a * a + b * b;
    }
#pragma unroll
  for (int m = 1; m < 16; m <<= 1)
#pragma unroll
    for (int mi = 0; mi < 2; ++mi)
#pragma unroll
      for (int j = 0; j < 4; ++j) {
        ps[mi][j] += __shfl_xor(ps[mi][j], m);
        pq[mi][j] += __shfl_xor(pq[mi][j], m);
      }
  if (lrow == 0)
#pragma unroll
    for (int mi = 0; mi < 2; ++mi)
#pragma unroll
      for (int j = 0; j < 4; ++j) {
        int rl = mi * 16 + lhi * 4 + j;
        atomicAdd(&red[rl * 2], ps[mi][j]);
        atomicAdd(&red[rl * 2 + 1], pq[mi][j]);
      }
  __syncthreads();

  float gv[2], bv[2];
  gv[0] = gg[wcol0 + lrow]; gv[1] = gg[wcol0 + 16 + lrow];
  bv[0] = bb[wcol0 + lrow]; bv[1] = bb[wcol0 + 16 + lrow];
#pragma unroll
  for (int mi = 0; mi < 2; ++mi)
#pragma unroll
    for (int j = 0; j < 4; ++j) {
      int rl = mi * 16 + lhi * 4 + j;
      int grow = block0 + rl;
      if (grow < NNODES) {
        float mu = red[rl * 2] * (1.f / DD);
        float var = red[rl * 2 + 1] * (1.f / DD) - mu * mu;
        float rstd = rsqrtf(var + 1e-5f);
#pragma unroll
        for (int ni = 0; ni < 2; ++ni) {
          int c = wcol0 + ni * 16 + lrow;
          float nv = bf2f(xbf[(long long)grow * DD + c]) +
                     (acc[mi][ni][j] - mu) * rstd * gv[ni] + bv[ni];
          if (LAST) xout[(long long)grow * DD + c] = nv;
          else sm[rl * 136 + c] = f2bf(nv);
        }
      }
    }
  if (!LAST) {
    __syncthreads();
#pragma unroll
    for (int p = tid; p < 512; p += 256) {
      int r = p >> 4, off2 = (p & 15) * 8;
      int grow = block0 + r;
      if (grow < NNODES)
        *(bf16x8*)(xbf + (long long)grow * DD + off2) =
            *(const bf16x8*)(sm + r * 136 + off2);
    }
  }
}

extern "C" void kernel_launch(void* const* d_in, const int* in_sizes, int n_in,
                              void* d_out, int out_size, void* d_ws, size_t ws_size,
                              hipStream_t stream) {
  const float* x  = (const float*)d_in[0];
  const int* ei   = (const int*)d_in[1];
  const float* ea = (const float*)d_in[2];
  const float* eW1 = (const float*)d_in[3];
  const float* eb1 = (const float*)d_in[4];
  const float* eW2 = (const float*)d_in[5];
  const float* eb2 = (const float*)d_in[6];
  const float* eW3 = (const float*)d_in[7];
  const float* eb3 = (const float*)d_in[8];
  const float* eg  = (const float*)d_in[9];
  const float* ebt = (const float*)d_in[10];
  const float* nW1 = (const float*)d_in[11];
  const float* nb1 = (const float*)d_in[12];
  const float* nW2 = (const float*)d_in[13];
  const float* nb2 = (const float*)d_in[14];
  const float* nW3 = (const float*)d_in[15];
  const float* nb3 = (const float*)d_in[16];
  const float* ng  = (const float*)d_in[17];
  const float* nbt = (const float*)d_in[18];

  float* xout = (float*)d_out;                               // final x f32
  unsigned short* easlot =
      (unsigned short*)(xout + (size_t)NNODES * DD);          // [E] 512B slots

  // workspace: packed weights | x_bf | cursor | off | perm
  unsigned short* pk_eW1 = (unsigned short*)d_ws;
  unsigned short* pk_eW2 = pk_eW1 + (size_t)L_ITERS * 384 * DD;
  unsigned short* pk_eW3 = pk_eW2 + (size_t)L_ITERS * DD * DD;
  unsigned short* pk_nW1 = pk_eW3 + (size_t)L_ITERS * DD * DD;
  unsigned short* pk_nW2 = pk_nW1 + (size_t)L_ITERS * 256 * DD;
  unsigned short* pk_nW3 = pk_nW2 + (size_t)L_ITERS * DD * DD;
  unsigned short* xbf = pk_nW3 + (size_t)L_ITERS * DD * DD;
  int* cursor = (int*)(xbf + (size_t)NNODES * DD);
  int* off    = cursor + NNODES;
  int* perm   = off + NNODES + 1;
  size_t need = (size_t)((char*)(perm + NEDGES) - (char*)d_ws);
  if (ws_size < need) return;

  pack_w_kernel<<<1024, 256, 0, stream>>>(eW1, pk_eW1, 384);
  pack_w_kernel<<<1024, 256, 0, stream>>>(eW2, pk_eW2, 128);
  pack_w_kernel<<<1024, 256, 0, stream>>>(eW3, pk_eW3, 128);
  pack_w_kernel<<<1024, 256, 0, stream>>>(nW1, pk_nW1, 256);
  pack_w_kernel<<<1024, 256, 0, stream>>>(nW2, pk_nW2, 128);
  pack_w_kernel<<<1024, 256, 0, stream>>>(nW3, pk_nW3, 128);

  cvt_kernel<<<1024, 256, 0, stream>>>(x, xbf, NNODES, 128);
  cvt_kernel<<<4096, 256, 0, stream>>>(ea, easlot, NEDGES, 256);

  hipMemsetAsync(cursor, 0, NNODES * sizeof(int), stream);
  hist_kernel<<<2048, 256, 0, stream>>>(ei, cursor);
  scan_kernel<<<1, 1024, 0, stream>>>(cursor, off, cursor);
  scatter_kernel<<<2048, 256, 0, stream>>>(ei, cursor, perm);

  for (int l = 0; l < L_ITERS; ++l) {
    if (l < L_ITERS - 1) {
      edge_kernel<false><<<NEDGES / 64, 256, 0, stream>>>(
          xbf, easlot, ei,
          pk_eW1 + (size_t)l * 384 * DD, pk_eW2 + (size_t)l * DD * DD,
          pk_eW3 + (size_t)l * DD * DD,
          eb1 + l * DD, eb2 + l * DD, eb3 + l * DD, eg + l * DD, ebt + l * DD);
      node_kernel<false><<<(NNODES + 31) / 32, 256, 0, stream>>>(
          xbf, easlot, xout, off, perm,
          pk_nW1 + (size_t)l * 256 * DD, pk_nW2 + (size_t)l * DD * DD,
          pk_nW3 + (size_t)l * DD * DD,
          nb1 + l * DD, nb2 + l * DD, nb3 + l * DD, ng + l * DD, nbt + l * DD);
    } else {
      edge_kernel<true><<<NEDGES / 64, 256, 0, stream>>>(
          xbf, easlot, ei,
          pk_eW1 + (size_t)l * 384 * DD, pk_eW2 + (size_t)l * DD * DD,
          pk_eW3 + (size_t)l * DD * DD,
          eb1 + l * DD, eb2 + l * DD, eb3 + l * DD, eg + l * DD, ebt + l * DD);
      node_kernel<true><<<(NNODES + 31) / 32, 256, 0, stream>>>(
          xbf, easlot, xout, off, perm,
          pk_nW1 + (size_t)l * 256 * DD, pk_nW2 + (size_t)l * DD * DD,
          pk_nW3 + (size_t)l * DD * DD,
          nb1 + l * DD, nb2 + l * DD, nb3 + l * DD, ng + l * DD, nbt + l * DD);
    }
  }
}

// Round 15
// 4404.586 us; speedup vs baseline: 1.4670x; 1.0184x over previous
//
#include <hip/hip_runtime.h>
#include <hip/hip_bf16.h>

#define L_ITERS 15
#define DD 128
#define NNODES 50000
#define NEDGES 800000

typedef __attribute__((ext_vector_type(4))) float f32x4;
typedef __attribute__((ext_vector_type(8))) short bf16x8;
typedef __attribute__((ext_vector_type(4))) short bf16x4;

// Native bf16 converts: compiler emits HW cvt (and fuses v_cvt_pk_bf16_f32).
static __device__ __forceinline__ unsigned short f2bf(float f) {
  union { __bf16 b; unsigned short u; } c;
  c.b = (__bf16)f;
  return c.u;
}
static __device__ __forceinline__ float bf2f(unsigned short h) {
  union { unsigned short u; __bf16 b; } c;
  c.u = h;
  return (float)c.b;
}

// Pack f32 weight [L][K][128] into MFMA B-fragment order (bf16):
// lane l of k-step s, n-frag t holds B[s*32 + (l>>4)*8 + j][t*16 + (l&15)], j=0..7
__global__ void pack_w_kernel(const float* __restrict__ src,
                              unsigned short* __restrict__ dst, int K) {
  int total = L_ITERS * K * DD;
  for (int i = blockIdx.x * blockDim.x + threadIdx.x; i < total;
       i += gridDim.x * blockDim.x) {
    int layer = i / (K * DD);
    int rem = i - layer * K * DD;
    int k = rem / DD, n = rem - (rem / DD) * DD;
    int s = k >> 5, hi = (k >> 3) & 3, j = k & 7;
    int t = n >> 4, lane = hi * 16 + (n & 15);
    dst[layer * K * DD + ((s * 8 + t) * 64 + lane) * 8 + j] = f2bf(src[i]);
  }
}

// f32 [rows][128] -> bf16 rows with dst row stride (shorts)
__global__ void cvt_kernel(const float* __restrict__ src,
                           unsigned short* __restrict__ dst,
                           int nrows, int dstride) {
  int total = nrows * 16;
  for (int p = blockIdx.x * blockDim.x + threadIdx.x; p < total;
       p += gridDim.x * blockDim.x) {
    int r = p >> 4, w = p & 15;
    const float* s = src + (long long)r * DD + w * 8;
    f32x4 a = *(const f32x4*)s, b = *(const f32x4*)(s + 4);
    bf16x8 o;
    o[0] = (short)f2bf(a[0]); o[1] = (short)f2bf(a[1]);
    o[2] = (short)f2bf(a[2]); o[3] = (short)f2bf(a[3]);
    o[4] = (short)f2bf(b[0]); o[5] = (short)f2bf(b[1]);
    o[6] = (short)f2bf(b[2]); o[7] = (short)f2bf(b[3]);
    *(bf16x8*)(dst + (long long)r * dstride + w * 8) = o;
  }
}

// ---------- CSR preprocessing (once per call) ----------
__global__ void hist_kernel(const int* __restrict__ ei, int* __restrict__ cnt) {
  for (int e = blockIdx.x * blockDim.x + threadIdx.x; e < NEDGES;
       e += gridDim.x * blockDim.x)
    atomicAdd(&cnt[ei[NEDGES + e]], 1);
}

__global__ __launch_bounds__(1024) void scan_kernel(const int* __restrict__ cnt,
                                                    int* __restrict__ off,
                                                    int* __restrict__ cursor) {
  __shared__ int buf[1024];
  __shared__ int base;
  if (threadIdx.x == 0) { base = 0; off[0] = 0; }
  __syncthreads();
  for (int start = 0; start < NNODES; start += 1024) {
    int i = start + threadIdx.x;
    int v = (i < NNODES) ? cnt[i] : 0;
    buf[threadIdx.x] = v;
    __syncthreads();
    for (int d = 1; d < 1024; d <<= 1) {
      int t = (threadIdx.x >= d) ? buf[threadIdx.x - d] : 0;
      __syncthreads();
      buf[threadIdx.x] += t;
      __syncthreads();
    }
    if (i < NNODES) {
      int incl = base + buf[threadIdx.x];
      off[i + 1] = incl;
      cursor[i] = incl - v;   // exclusive start
    }
    __syncthreads();
    if (threadIdx.x == 0) base += buf[1023];
    __syncthreads();
  }
}

__global__ void scatter_kernel(const int* __restrict__ ei, int* __restrict__ cursor,
                               int* __restrict__ perm) {
  for (int e = blockIdx.x * blockDim.x + threadIdx.x; e < NEDGES;
       e += gridDim.x * blockDim.x) {
    int p = atomicAdd(&cursor[ei[NEDGES + e]], 1);
    perm[p] = e;
  }
}

// ---------- GEMM pieces ----------
// A in LDS, plane-major [(NS+3)/4][ROWS][136] bf16. acc = A @ Wpacked + bias.
// ROT: H planes store col' = (col + 16*((row>>2)&3)) & 127 — kills the 4-way
// bank conflict on relu b16 writes while keeping b128 reads at the 8/quad
// floor (rotation is a multiple of 8 shorts -> alignment preserved).
template <int NS, int ROWS, int MI, bool ROT>
static __device__ __forceinline__ void gemm_step(
    const unsigned short* A, const unsigned short* __restrict__ pw,
    const float* __restrict__ bias, f32x4 (&acc)[MI][2],
    int lrow, int lhi, int lane, int wv, int wcol0) {
  float bv0 = bias[wcol0 + lrow];
  float bv1 = bias[wcol0 + 16 + lrow];
#pragma unroll
  for (int mi = 0; mi < MI; ++mi) {
    f32x4 z0, z1;
    z0[0] = bv0; z0[1] = bv0; z0[2] = bv0; z0[3] = bv0;
    z1[0] = bv1; z1[1] = bv1; z1[2] = bv1; z1[3] = bv1;
    acc[mi][0] = z0; acc[mi][1] = z1;
  }
  const unsigned short* bp = pw + (wv * 2 * 64 + lane) * 8;
  const int rot = ROT ? (((lrow >> 2) & 3) * 16) : 0;  // row-group rotation
#pragma unroll
  for (int s = 0; s < NS; ++s) {
    bf16x8 w0 = *(const bf16x8*)(bp + s * 4096);
    bf16x8 w1 = *(const bf16x8*)(bp + s * 4096 + 512);
    int colbase = (s & 3) * 32 + lhi * 8;
    if (ROT) colbase = (colbase + rot) & 127;
    const unsigned short* ap = A + (s >> 2) * (ROWS * 136) + colbase;
#pragma unroll
    for (int mi = 0; mi < MI; ++mi) {
      bf16x8 a = *(const bf16x8*)(ap + (mi * 16 + lrow) * 136);
      acc[mi][0] = __builtin_amdgcn_mfma_f32_16x16x32_bf16(a, w0, acc[mi][0], 0, 0, 0);
      acc[mi][1] = __builtin_amdgcn_mfma_f32_16x16x32_bf16(a, w1, acc[mi][1], 0, 0, 0);
    }
  }
}

template <int MI, bool ROT>
static __device__ __forceinline__ void relu_store(const f32x4 (&acc)[MI][2],
                                                  unsigned short* H,
                                                  int lrow, int lhi, int wcol0) {
#pragma unroll
  for (int mi = 0; mi < MI; ++mi)
#pragma unroll
    for (int ni = 0; ni < 2; ++ni)
#pragma unroll
      for (int j = 0; j < 4; ++j) {
        int col = wcol0 + ni * 16 + lrow;
        if (ROT) col = (col + lhi * 16) & 127;   // row-group = lhi here
        H[(mi * 16 + lhi * 4 + j) * 136 + col] =
            f2bf(fmaxf(acc[mi][ni][j], 0.f));
      }
}

// ---------- edge MLP: 64 edges/block, 3 LDS planes, vector epilogue ----------
// easlot: [E] slots of 256 shorts (=512B). Iterations keep bf16 row in first
// 128 shorts; LAST writes the full slot as 128 f32 (the final output).
template <bool LAST>
__global__ __launch_bounds__(256) void edge_kernel(
    const unsigned short* __restrict__ xbf, unsigned short* easlot,
    const int* __restrict__ ei,
    const unsigned short* __restrict__ pw1,
    const unsigned short* __restrict__ pw2,
    const unsigned short* __restrict__ pw3,
    const float* __restrict__ b1, const float* __restrict__ b2,
    const float* __restrict__ b3, const float* __restrict__ gg,
    const float* __restrict__ bb) {
  __shared__ unsigned short sm[3 * 64 * 136];  // P0=x_src P1=x_dst P2=ea
  constexpr int PL = 64 * 136;
  const int tid = threadIdx.x, lane = tid & 63, wv = tid >> 6;
  const int lrow = lane & 15, lhi = lane >> 4, wcol0 = wv * 32;
  const long long block0 = (long long)blockIdx.x * 64;  // NEDGES % 64 == 0

  { // stage A: pure 16B bf16 copies; 4 threads/row, 12 pieces each
    int r = tid >> 2, q = tid & 3;
    long long e = block0 + r;
    const unsigned short* s0 = xbf + (long long)ei[e] * DD;
    const unsigned short* s1 = xbf + (long long)ei[NEDGES + e] * DD;
    const unsigned short* s2 = easlot + e * 256;
#pragma unroll
    for (int k = 0; k < 12; ++k) {
      int w = q + 4 * k;
      int plane = w >> 4, off = (w & 15) * 8;
      const unsigned short* sp = (plane == 0) ? s0 : (plane == 1 ? s1 : s2);
      *(bf16x8*)(&sm[plane * PL + r * 136 + off]) = *(const bf16x8*)(sp + off);
    }
  }
  __syncthreads();

  f32x4 acc[4][2];
  gemm_step<12, 64, 4, false>(sm, pw1, b1, acc, lrow, lhi, lane, wv, wcol0);
  __syncthreads();                          // P0 (x_src) dead -> H1
  relu_store<4, true>(acc, sm, lrow, lhi, wcol0);
  __syncthreads();
  gemm_step<4, 64, 4, true>(sm, pw2, b2, acc, lrow, lhi, lane, wv, wcol0);
  relu_store<4, true>(acc, sm + PL, lrow, lhi, wcol0);   // P1 (x_dst) dead
  __syncthreads();
  gemm_step<4, 64, 4, true>(sm + PL, pw3, b3, acc, lrow, lhi, lane, wv, wcol0);
  __syncthreads();                          // all H2 (P1) reads done

  // acc -> F f32 [64][132] over P0+P1 (33792B <= 34816B); stride 132 keeps
  // the later b128 row reads at the 8-lane/bank-group floor.
  float* F = (float*)sm;
#pragma unroll
  for (int mi = 0; mi < 4; ++mi)
#pragma unroll
    for (int ni = 0; ni < 2; ++ni)
#pragma unroll
      for (int j = 0; j < 4; ++j)
        F[(mi * 16 + lhi * 4 + j) * 132 + wcol0 + ni * 16 + lrow] =
            acc[mi][ni][j];
  __syncthreads();

  // 8 threads/row, 2 row passes. Thread q of row r owns cols so that each
  // store instruction writes 8 threads x 16B = 128B aligned per row.
  const int r0 = tid >> 3, q = tid & 7;
  const unsigned short* P2 = sm + 2 * PL;   // original ea bf16 (intact)
  float* eaf = (float*)easlot;
#pragma unroll
  for (int pass = 0; pass < 2; ++pass) {
    const int r = r0 + pass * 32;
    const long long e = block0 + r;
    float av[16];
    double s = 0.0, q2 = 0.0;
    if (!LAST) {
#pragma unroll
      for (int k = 0; k < 2; ++k) {         // 8 cols per k: c0 = 8q + 64k
        int c0 = 8 * q + 64 * k;
        f32x4 u0 = *(const f32x4*)(F + r * 132 + c0);
        f32x4 u1 = *(const f32x4*)(F + r * 132 + c0 + 4);
#pragma unroll
        for (int i = 0; i < 4; ++i) {
          double d0 = (double)u0[i], d1 = (double)u1[i];
          av[8 * k + i] = u0[i];     s += d0; q2 += d0 * d0;
          av[8 * k + 4 + i] = u1[i]; s += d1; q2 += d1 * d1;
        }
      }
    } else {
#pragma unroll
      for (int k = 0; k < 4; ++k) {         // 4 cols per k: c0 = 4q + 32k
        int c0 = 4 * q + 32 * k;
        f32x4 u = *(const f32x4*)(F + r * 132 + c0);
#pragma unroll
        for (int i = 0; i < 4; ++i) {
          double d = (double)u[i];
          av[4 * k + i] = u[i]; s += d; q2 += d * d;
        }
      }
    }
    // butterfly over the 8 threads of this row (lanes differ by 1,2,4)
    s += __shfl_xor(s, 1);  s += __shfl_xor(s, 2);  s += __shfl_xor(s, 4);
    q2 += __shfl_xor(q2, 1); q2 += __shfl_xor(q2, 2); q2 += __shfl_xor(q2, 4);
    double mu_d = s * (1.0 / DD);
    double var_d = q2 * (1.0 / DD) - mu_d * mu_d;
    float mu = (float)mu_d;
    float rstd = rsqrtf((float)var_d + 1e-5f);

    if (!LAST) {
#pragma unroll
      for (int k = 0; k < 2; ++k) {
        int c0 = 8 * q + 64 * k;
        bf16x8 rv = *(const bf16x8*)(P2 + r * 136 + c0);
        f32x4 g0 = *(const f32x4*)(gg + c0), g1 = *(const f32x4*)(gg + c0 + 4);
        f32x4 t0 = *(const f32x4*)(bb + c0), t1 = *(const f32x4*)(bb + c0 + 4);
        bf16x8 o;
#pragma unroll
        for (int i = 0; i < 4; ++i) {
          o[i] = (short)f2bf(bf2f((unsigned short)rv[i]) +
                             (av[8 * k + i] - mu) * rstd * g0[i] + t0[i]);
          o[4 + i] = (short)f2bf(bf2f((unsigned short)rv[4 + i]) +
                                 (av[8 * k + 4 + i] - mu) * rstd * g1[i] + t1[i]);
        }
        *(bf16x8*)(easlot + e * 256 + c0) = o;   // 8 threads -> 128B line
      }
    } else {
#pragma unroll
      for (int k = 0; k < 4; ++k) {
        int c0 = 4 * q + 32 * k;
        bf16x4 rv = *(const bf16x4*)(P2 + r * 136 + c0);
        f32x4 g0 = *(const f32x4*)(gg + c0);
        f32x4 t0 = *(const f32x4*)(bb + c0);
        f32x4 o;
#pragma unroll
        for (int i = 0; i < 4; ++i)
          o[i] = bf2f((unsigned short)rv[i]) +
                 (av[4 * k + i] - mu) * rstd * g0[i] + t0[i];
        *(f32x4*)(eaf + e * 128 + c0) = o;       // 8 threads -> 128B line
      }
    }
  }
}

// ---------- node MLP: 32 nodes/block, CSR segment-sum, bf16 state ----------
template <bool LAST>
__global__ __launch_bounds__(256) void node_kernel(
    unsigned short* xbf, const unsigned short* __restrict__ easlot,
    float* xout,
    const int* __restrict__ off, const int* __restrict__ perm,
    const unsigned short* __restrict__ pw1,
    const unsigned short* __restrict__ pw2,
    const unsigned short* __restrict__ pw3,
    const float* __restrict__ b1, const float* __restrict__ b2,
    const float* __restrict__ b3, const float* __restrict__ gg,
    const float* __restrict__ bb) {
  __shared__ unsigned short sm[2 * 32 * 136];  // P0=x P1=agg
  __shared__ float red[64];
  constexpr int PL = 32 * 136;
  const int tid = threadIdx.x, lane = tid & 63, wv = tid >> 6;
  const int lrow = lane & 15, lhi = lane >> 4, wcol0 = wv * 32;
  const int block0 = blockIdx.x * 32;

  if (tid < 64) red[tid] = 0.f;

  { // stage A: x copy + f32-accumulated segment sum of ea
    int r = tid >> 3, c8 = tid & 7;
    int grow = block0 + r;
    int gr = grow < NNODES ? grow : NNODES - 1;
    const unsigned short* xs = xbf + (long long)gr * DD + c8 * 16;
    *(bf16x8*)(&sm[r * 136 + c8 * 16]) = *(const bf16x8*)xs;
    *(bf16x8*)(&sm[r * 136 + c8 * 16 + 8]) = *(const bf16x8*)(xs + 8);
    float a[16];
#pragma unroll
    for (int i = 0; i < 16; ++i) a[i] = 0.f;
    int p0 = off[gr], p1 = off[gr + 1];
    if (!LAST) {
      for (int p = p0; p < p1; ++p) {
        const unsigned short* ep = easlot + (long long)perm[p] * 256 + c8 * 16;
        bf16x8 u = *(const bf16x8*)ep;
        bf16x8 v = *(const bf16x8*)(ep + 8);
#pragma unroll
        for (int i = 0; i < 8; ++i) {
          a[i] += bf2f((unsigned short)u[i]);
          a[8 + i] += bf2f((unsigned short)v[i]);
        }
      }
    } else {
      const float* eaf = (const float*)easlot;
      for (int p = p0; p < p1; ++p) {
        const float* ep = eaf + (long long)perm[p] * 128 + c8 * 16;
        f32x4 u0 = *(const f32x4*)ep, u1 = *(const f32x4*)(ep + 4);
        f32x4 u2 = *(const f32x4*)(ep + 8), u3 = *(const f32x4*)(ep + 12);
#pragma unroll
        for (int i = 0; i < 4; ++i) {
          a[i] += u0[i]; a[4 + i] += u1[i]; a[8 + i] += u2[i]; a[12 + i] += u3[i];
        }
      }
    }
    bf16x8 o0, o1;
#pragma unroll
    for (int i = 0; i < 8; ++i) {
      o0[i] = (short)f2bf(a[i]);
      o1[i] = (short)f2bf(a[8 + i]);
    }
    *(bf16x8*)(&sm[PL + r * 136 + c8 * 16]) = o0;
    *(bf16x8*)(&sm[PL + r * 136 + c8 * 16 + 8]) = o1;
  }
  __syncthreads();

  f32x4 acc[2][2];
  gemm_step<8, 32, 2, false>(sm, pw1, b1, acc, lrow, lhi, lane, wv, wcol0);
  __syncthreads();
  relu_store<2, true>(acc, sm, lrow, lhi, wcol0);
  __syncthreads();
  gemm_step<4, 32, 2, true>(sm, pw2, b2, acc, lrow, lhi, lane, wv, wcol0);
  relu_store<2, true>(acc, sm + PL, lrow, lhi, wcol0);
  __syncthreads();
  gemm_step<4, 32, 2, true>(sm + PL, pw3, b3, acc, lrow, lhi, lane, wv, wcol0);

  float ps[2][4], pq[2][4];
#pragma unroll
  for (int mi = 0; mi < 2; ++mi)
#pragma unroll
    for (int j = 0; j < 4; ++j) {
      float a = acc[mi][0][j], b = acc[mi][1][j];
      ps[mi][j] = a + b;
      pq[mi][j] = a * a + b * b;
    }
#pragma unroll
  for (int m = 1; m < 16; m <<= 1)
#pragma unroll
    for (int mi = 0; mi < 2; ++mi)
#pragma unroll
      for (int j = 0; j < 4; ++j) {
        ps[mi][j] += __shfl_xor(ps[mi][j], m);
        pq[mi][j] += __shfl_xor(pq[mi][j], m);
      }
  if (lrow == 0)
#pragma unroll
    for (int mi = 0; mi < 2; ++mi)
#pragma unroll
      for (int j = 0; j < 4; ++j) {
        int rl = mi * 16 + lhi * 4 + j;
        atomicAdd(&red[rl * 2], ps[mi][j]);
        atomicAdd(&red[rl * 2 + 1], pq[mi][j]);
      }
  __syncthreads();

  float gv[2], bv[2];
  gv[0] = gg[wcol0 + lrow]; gv[1] = gg[wcol0 + 16 + lrow];
  bv[0] = bb[wcol0 + lrow]; bv[1] = bb[wcol0 + 16 + lrow];
#pragma unroll
  for (int mi = 0; mi < 2; ++mi)
#pragma unroll
    for (int j = 0; j < 4; ++j) {
      int rl = mi * 16 + lhi * 4 + j;
      int grow = block0 + rl;
      if (grow < NNODES) {
        float mu = red[rl * 2] * (1.f / DD);
        float var = red[rl * 2 + 1] * (1.f / DD) - mu * mu;
        float rstd = rsqrtf(var + 1e-5f);
#pragma unroll
        for (int ni = 0; ni < 2; ++ni) {
          int c = wcol0 + ni * 16 + lrow;
          float nv = bf2f(xbf[(long long)grow * DD + c]) +
                     (acc[mi][ni][j] - mu) * rstd * gv[ni] + bv[ni];
          if (LAST) xout[(long long)grow * DD + c] = nv;
          else sm[rl * 136 + c] = f2bf(nv);
        }
      }
    }
  if (!LAST) {
    __syncthreads();
#pragma unroll
    for (int p = tid; p < 512; p += 256) {
      int r = p >> 4, off2 = (p & 15) * 8;
      int grow = block0 + r;
      if (grow < NNODES)
        *(bf16x8*)(xbf + (long long)grow * DD + off2) =
            *(const bf16x8*)(sm + r * 136 + off2);
    }
  }
}

extern "C" void kernel_launch(void* const* d_in, const int* in_sizes, int n_in,
                              void* d_out, int out_size, void* d_ws, size_t ws_size,
                              hipStream_t stream) {
  const float* x  = (const float*)d_in[0];
  const int* ei   = (const int*)d_in[1];
  const float* ea = (const float*)d_in[2];
  const float* eW1 = (const float*)d_in[3];
  const float* eb1 = (const float*)d_in[4];
  const float* eW2 = (const float*)d_in[5];
  const float* eb2 = (const float*)d_in[6];
  const float* eW3 = (const float*)d_in[7];
  const float* eb3 = (const float*)d_in[8];
  const float* eg  = (const float*)d_in[9];
  const float* ebt = (const float*)d_in[10];
  const float* nW1 = (const float*)d_in[11];
  const float* nb1 = (const float*)d_in[12];
  const float* nW2 = (const float*)d_in[13];
  const float* nb2 = (const float*)d_in[14];
  const float* nW3 = (const float*)d_in[15];
  const float* nb3 = (const float*)d_in[16];
  const float* ng  = (const float*)d_in[17];
  const float* nbt = (const float*)d_in[18];

  float* xout = (float*)d_out;                               // final x f32
  unsigned short* easlot =
      (unsigned short*)(xout + (size_t)NNODES * DD);          // [E] 512B slots

  // workspace: packed weights | x_bf | cursor | off | perm
  unsigned short* pk_eW1 = (unsigned short*)d_ws;
  unsigned short* pk_eW2 = pk_eW1 + (size_t)L_ITERS * 384 * DD;
  unsigned short* pk_eW3 = pk_eW2 + (size_t)L_ITERS * DD * DD;
  unsigned short* pk_nW1 = pk_eW3 + (size_t)L_ITERS * DD * DD;
  unsigned short* pk_nW2 = pk_nW1 + (size_t)L_ITERS * 256 * DD;
  unsigned short* pk_nW3 = pk_nW2 + (size_t)L_ITERS * DD * DD;
  unsigned short* xbf = pk_nW3 + (size_t)L_ITERS * DD * DD;
  int* cursor = (int*)(xbf + (size_t)NNODES * DD);
  int* off    = cursor + NNODES;
  int* perm   = off + NNODES + 1;
  size_t need = (size_t)((char*)(perm + NEDGES) - (char*)d_ws);
  if (ws_size < need) return;

  pack_w_kernel<<<1024, 256, 0, stream>>>(eW1, pk_eW1, 384);
  pack_w_kernel<<<1024, 256, 0, stream>>>(eW2, pk_eW2, 128);
  pack_w_kernel<<<1024, 256, 0, stream>>>(eW3, pk_eW3, 128);
  pack_w_kernel<<<1024, 256, 0, stream>>>(nW1, pk_nW1, 256);
  pack_w_kernel<<<1024, 256, 0, stream>>>(nW2, pk_nW2, 128);
  pack_w_kernel<<<1024, 256, 0, stream>>>(nW3, pk_nW3, 128);

  cvt_kernel<<<1024, 256, 0, stream>>>(x, xbf, NNODES, 128);
  cvt_kernel<<<4096, 256, 0, stream>>>(ea, easlot, NEDGES, 256);

  hipMemsetAsync(cursor, 0, NNODES * sizeof(int), stream);
  hist_kernel<<<2048, 256, 0, stream>>>(ei, cursor);
  scan_kernel<<<1, 1024, 0, stream>>>(cursor, off, cursor);
  scatter_kernel<<<2048, 256, 0, stream>>>(ei, cursor, perm);

  for (int l = 0; l < L_ITERS; ++l) {
    if (l < L_ITERS - 1) {
      edge_kernel<false><<<NEDGES / 64, 256, 0, stream>>>(
          xbf, easlot, ei,
          pk_eW1 + (size_t)l * 384 * DD, pk_eW2 + (size_t)l * DD * DD,
          pk_eW3 + (size_t)l * DD * DD,
          eb1 + l * DD, eb2 + l * DD, eb3 + l * DD, eg + l * DD, ebt + l * DD);
      node_kernel<false><<<(NNODES + 31) / 32, 256, 0, stream>>>(
          xbf, easlot, xout, off, perm,
          pk_nW1 + (size_t)l * 256 * DD, pk_nW2 + (size_t)l * DD * DD,
          pk_nW3 + (size_t)l * DD * DD,
          nb1 + l * DD, nb2 + l * DD, nb3 + l * DD, ng + l * DD, nbt + l * DD);
    } else {
      edge_kernel<true><<<NEDGES / 64, 256, 0, stream>>>(
          xbf, easlot, ei,
          pk_eW1 + (size_t)l * 384 * DD, pk_eW2 + (size_t)l * DD * DD,
          pk_eW3 + (size_t)l * DD * DD,
          eb1 + l * DD, eb2 + l * DD, eb3 + l * DD, eg + l * DD, ebt + l * DD);
      node_kernel<true><<<(NNODES + 31) / 32, 256, 0, stream>>>(
          xbf, easlot, xout, off, perm,
          pk_nW1 + (size_t)l * 256 * DD, pk_nW2 + (size_t)l * DD * DD,
          pk_nW3 + (size_t)l * DD * DD,
          nb1 + l * DD, nb2 + l * DD, nb3 + l * DD, ng + l * DD, nbt + l * DD);
    }
  }
}